// Round 11
// baseline (23519.167 us; speedup 1.0000x reference)
//
#include <hip/hip_runtime.h>

#define BB 64
#define SS 196
#define EE 512
#define DD 2048
#define MM 25
#define HNN 32
#define NHH 8
#define TT 50
#define NSS 512
#define OUTN 1000
#define HDD 64
#define KSYN 2560
#define NSYN 4096

#define CERT_OFF 3200000
#define SYNC_OFF 3206400

__device__ __forceinline__ float sigm(float x){ return 1.f / (1.f + expf(-x)); }
__device__ __forceinline__ int rfl(int x){ return __builtin_amdgcn_readfirstlane(x); }

// relaxed agent-scope (cross-XCD coherent) load/store
__device__ __forceinline__ float ald(const float* p){
  return __hip_atomic_load(p, __ATOMIC_RELAXED, __HIP_MEMORY_SCOPE_AGENT);
}
__device__ __forceinline__ void ast(float* p, float v){
  __hip_atomic_store(p, v, __ATOMIC_RELAXED, __HIP_MEMORY_SCOPE_AGENT);
}

// ---------------- f32 GEMM (precompute) ----------------
// LAYOUT 0: row-major. 1: vh permute ((b*8+h)*196+s)*64+d. 3: khT ((b*8+h)*64+d)*196+s.
template<int LAYOUT>
__global__ __launch_bounds__(256) void sgemm(
    const float* __restrict__ Ag, const float* __restrict__ Wg,
    const float* __restrict__ bias, float* __restrict__ Cg,
    int Mg, int Ng, int Kg, int ro)
{
  __shared__ float As[16][68];
  __shared__ float Bs[16][68];
  int t = threadIdx.x;
  int bm = blockIdx.x * 64, bn = blockIdx.y * 64;
  int ty = t >> 4, tx = t & 15;
  int atm = t >> 2, atk = (t & 3) * 4;
  int bkk = t >> 4, bnn = (t & 15) * 4;
  float c[4][4] = {};
  for (int k0 = 0; k0 < Kg; k0 += 16){
    float4 av = *reinterpret_cast<const float4*>(Ag + (size_t)(bm + atm) * Kg + k0 + atk);
    As[atk][atm] = av.x; As[atk + 1][atm] = av.y;
    As[atk + 2][atm] = av.z; As[atk + 3][atm] = av.w;
    float4 bv = *reinterpret_cast<const float4*>(Wg + (size_t)(k0 + bkk) * Ng + bn + bnn);
    *reinterpret_cast<float4*>(&Bs[bkk][bnn]) = bv;
    __syncthreads();
    #pragma unroll
    for (int k = 0; k < 16; k++){
      float4 a = *reinterpret_cast<const float4*>(&As[k][ty * 4]);
      float4 b = *reinterpret_cast<const float4*>(&Bs[k][tx * 4]);
      c[0][0] += a.x * b.x; c[0][1] += a.x * b.y; c[0][2] += a.x * b.z; c[0][3] += a.x * b.w;
      c[1][0] += a.y * b.x; c[1][1] += a.y * b.y; c[1][2] += a.y * b.z; c[1][3] += a.y * b.w;
      c[2][0] += a.z * b.x; c[2][1] += a.z * b.y; c[2][2] += a.z * b.z; c[2][3] += a.z * b.w;
      c[3][0] += a.w * b.x; c[3][1] += a.w * b.y; c[3][2] += a.w * b.z; c[3][3] += a.w * b.w;
    }
    __syncthreads();
  }
  #pragma unroll
  for (int j = 0; j < 4; j++){
    int col = bn + tx * 4 + j;
    float bvv = bias ? bias[col] : 0.f;
    #pragma unroll
    for (int i = 0; i < 4; i++){
      int row = bm + ty * 4 + i;
      float v = c[i][j] + bvv;
      if (LAYOUT == 0){
        Cg[(size_t)row * Ng + col] = v;
      } else {
        int tok = ro + row;
        int b = tok / SS, s = tok - b * SS;
        int h = col >> 6, dh = col & 63;
        if (LAYOUT == 1) Cg[(((size_t)b * NHH + h) * SS + s) * HDD + dh] = v;
        else             Cg[(((size_t)b * NHH + h) * HDD + dh) * SS + s] = v;
      }
    }
  }
}

// ---------------- LayerNorm rows ----------------
__global__ __launch_bounds__(256) void ln_rows_kernel(const float* __restrict__ y,
    const float* __restrict__ g, const float* __restrict__ bb,
    float* __restrict__ outf)
{
  int r = blockIdx.x, t = threadIdx.x;
  __shared__ float red[256];
  const float* row = y + (size_t)r * EE;
  float v0 = row[t], v1 = row[t + 256];
  red[t] = v0 + v1; __syncthreads();
  for (int st = 128; st > 0; st >>= 1){ if (t < st) red[t] += red[t + st]; __syncthreads(); }
  float mean = red[0] * (1.f / EE); __syncthreads();
  float d0 = v0 - mean, d1 = v1 - mean;
  red[t] = d0 * d0 + d1 * d1; __syncthreads();
  for (int st = 128; st > 0; st >>= 1){ if (t < st) red[t] += red[t + st]; __syncthreads(); }
  float rs = 1.f / sqrtf(red[0] * (1.f / EE) + 1e-5f);
  float* orow = outf + (size_t)r * EE;
  orow[t] = d0 * rs * g[t] + bb[t];
  orow[t + 256] = d1 * rs * g[t + 256] + bb[t + 256];
}

// ---------------- bqq = bq @ Wqa + bqa ----------------
__global__ __launch_bounds__(512) void bqq_kernel(const float* __restrict__ bq,
    const float* __restrict__ Wqa, const float* __restrict__ bqa, float* __restrict__ bqq)
{
  __shared__ float s[EE];
  int t = threadIdx.x;
  s[t] = bq[t]; __syncthreads();
  float a0 = 0, a1 = 0, a2 = 0, a3 = 0;
  #pragma unroll 8
  for (int k = 0; k < EE; k += 4){
    a0 += s[k]     * Wqa[(size_t)(k)     * EE + t];
    a1 += s[k + 1] * Wqa[(size_t)(k + 1) * EE + t];
    a2 += s[k + 2] * Wqa[(size_t)(k + 2) * EE + t];
    a3 += s[k + 3] * Wqa[(size_t)(k + 3) * EE + t];
  }
  bqq[t] = bqa[t] + ((a0 + a1) + (a2 + a3));
}

// ---------------- decay -> rate ----------------
__global__ __launch_bounds__(512) void prep_decay(const float* __restrict__ dcA,
    const float* __restrict__ dcO, float* __restrict__ rA, float* __restrict__ rO)
{
  int t = threadIdx.x;
  rA[t] = expf(-fminf(fmaxf(dcA[t], 0.f), 15.f));
  rO[t] = expf(-fminf(fmaxf(dcO[t], 0.f), 15.f));
}

// ---------------- init state + flag/psum reset ----------------
// aA/bA/aO/bO layout: [b][n] (block-local to P1 block b)
__global__ __launch_bounds__(256) void init_kernel(const float* __restrict__ sa,
    const float* __restrict__ strace,
    const int* __restrict__ ol, const int* __restrict__ orr,
    float* __restrict__ act, float* __restrict__ tr,
    float* __restrict__ aA, float* __restrict__ bA,
    float* __restrict__ aO, float* __restrict__ bO,
    float* __restrict__ psum, float* __restrict__ psq,
    unsigned* __restrict__ flags)
{
  int tid = blockIdx.x * 256 + threadIdx.x;
  if (tid < 512) flags[tid] = 0u;
  if (tid < 64){ psum[tid] = 0.f; psq[tid] = 0.f; }
  int b = tid >> 11, d = tid & 2047;
  act[(size_t)d * 64 + b] = sa[d];
  for (int m = 0; m < MM; m++)
    tr[((size_t)m * DD + d) * 64 + b] = strace[d * MM + m];
  if (tid < BB * NSS){
    int n = tid & (NSS - 1);
    int b2 = tid >> 9;
    aO[(size_t)b2 * NSS + n] = sa[ol[n]] * sa[orr[n]];
    bO[(size_t)b2 * NSS + n] = 1.f;
    aA[(size_t)b2 * NSS + n] = 0.f;
    bA[(size_t)b2 * NSS + n] = 0.f;
  }
}

// ---------------- lean grid barrier (distributed flags, workgroup fences only) ----------------
__device__ __forceinline__ void gbar(unsigned* arrive, unsigned* release, unsigned g)
{
  __syncthreads();
  const int tid = threadIdx.x;
  if (blockIdx.x == 0){
    if (tid < 256){
      if (tid == 0){
        __builtin_amdgcn_fence(__ATOMIC_RELEASE, "workgroup");
        __hip_atomic_store(&arrive[0], g, __ATOMIC_RELAXED, __HIP_MEMORY_SCOPE_AGENT);
      }
      while (__hip_atomic_load(&arrive[tid], __ATOMIC_RELAXED, __HIP_MEMORY_SCOPE_AGENT) < g)
        __builtin_amdgcn_s_sleep(8);
    }
    __syncthreads();
    if (tid < 256)
      __hip_atomic_store(&release[tid], g, __ATOMIC_RELAXED, __HIP_MEMORY_SCOPE_AGENT);
    __builtin_amdgcn_fence(__ATOMIC_ACQUIRE, "workgroup");
    __syncthreads();
  } else {
    if (tid == 0){
      __builtin_amdgcn_fence(__ATOMIC_RELEASE, "workgroup");
      __hip_atomic_store(&arrive[blockIdx.x], g, __ATOMIC_RELAXED, __HIP_MEMORY_SCOPE_AGENT);
      while (__hip_atomic_load(&release[blockIdx.x], __ATOMIC_RELAXED, __HIP_MEMORY_SCOPE_AGENT) < g)
        __builtin_amdgcn_s_sleep(8);
      __builtin_amdgcn_fence(__ATOMIC_ACQUIRE, "workgroup");
    }
    __syncthreads();
  }
}

// ---------------- persistent step loop ----------------
struct CtmParams {
  const float *khT, *vh, *Wqq, *bqq, *Wo, *bo, *Wsyn, *bsyn, *gsyn, *bsn;
  const float *w1, *b1, *w2, *b2, *Wout, *bout, *rA, *rO;
  const int *ial, *iar, *iol, *ior;
  float *A, *act, *part, *psum, *psq, *aA, *bA, *aO, *bO, *tr, *dout;
  unsigned *flags;
};

__global__ __launch_bounds__(512, 1) void ctm_persist(CtmParams p)
{
  __shared__ float sm[20992];   // P2: A-slice 20480 | P3: w1s 12800 + smU @20480
  const int tid = threadIdx.x, blk = blockIdx.x;
  const int lane = tid & 63, wv = tid >> 6;
  unsigned g = 0;
  unsigned* arrive = p.flags;
  unsigned* release = p.flags + 256;

  for (int t = 0; t < TT; t++){
    // ========== P1: front (blocks 0..63 = batch b); block 64 zeroes psum ==========
    if (blk < BB){
      const int b = blk;
      // A: sA(t) + sO(t-1) state updates -> LDS
      {
        int n = tid;
        float pa = ald(&p.act[(size_t)p.ial[n] * 64 + b]) * ald(&p.act[(size_t)p.iar[n] * 64 + b]);
        float r = p.rA[n];
        float na = r * p.aA[(size_t)b * NSS + n] + pa;
        float nb = r * p.bA[(size_t)b * NSS + n] + 1.f;
        p.aA[(size_t)b * NSS + n] = na; p.bA[(size_t)b * NSS + n] = nb;
        sm[n] = na / sqrtf(nb);
        if (t > 0){
          float po = ald(&p.act[(size_t)p.iol[n] * 64 + b]) * ald(&p.act[(size_t)p.ior[n] * 64 + b]);
          float r2 = p.rO[n];
          float na2 = r2 * p.aO[(size_t)b * NSS + n] + po;
          float nb2 = r2 * p.bO[(size_t)b * NSS + n] + 1.f;
          p.aO[(size_t)b * NSS + n] = na2; p.bO[(size_t)b * NSS + n] = nb2;
          sm[512 + n] = na2 / sqrtf(nb2);
        }
      }
      __syncthreads();
      // B: q2 = sA @ Wqq + bqq
      {
        int e = tid;
        float a0 = 0, a1 = 0, a2 = 0, a3 = 0;
        #pragma unroll 8
        for (int k = 0; k < EE; k += 4){
          a0 += sm[k]     * p.Wqq[(size_t)(k)     * EE + e];
          a1 += sm[k + 1] * p.Wqq[(size_t)(k + 1) * EE + e];
          a2 += sm[k + 2] * p.Wqq[(size_t)(k + 2) * EE + e];
          a3 += sm[k + 3] * p.Wqq[(size_t)(k + 3) * EE + e];
        }
        sm[1024 + e] = p.bqq[e] + ((a0 + a1) + (a2 + a3));
      }
      __syncthreads();
      // C: attention (wave = head)
      {
        int h = wv;
        int u = b * NHH + h;
        const float* K = p.khT + (size_t)u * HDD * SS;
        const float* V = p.vh + (size_t)u * SS * HDD;
        float c0 = 0, c1 = 0, c2 = 0, c3 = 0;
        for (int d2 = 0; d2 < HDD; d2++){
          float qd = sm[1024 + h * 64 + d2];
          const float* Kr = K + (size_t)d2 * SS;
          c0 += qd * Kr[lane];
          c1 += qd * Kr[64 + lane];
          c2 += qd * Kr[128 + lane];
          c3 += qd * Kr[192 + lane];
        }
        float s0 = c0 * 0.125f, s1 = c1 * 0.125f, s2 = c2 * 0.125f;
        float s3 = (lane < 4) ? c3 * 0.125f : -1e30f;
        float mx = fmaxf(fmaxf(s0, s1), fmaxf(s2, s3));
        #pragma unroll
        for (int off = 32; off > 0; off >>= 1)
          mx = fmaxf(mx, __shfl_xor(mx, off, 64));
        float e0 = expf(s0 - mx), e1 = expf(s1 - mx), e2 = expf(s2 - mx);
        float e3 = (lane < 4) ? expf(s3 - mx) : 0.f;
        float dn = e0 + e1 + e2 + e3;
        #pragma unroll
        for (int off = 32; off > 0; off >>= 1)
          dn += __shfl_xor(dn, off, 64);
        float* ps = sm + 1536 + h * 224;
        ps[lane] = e0; ps[64 + lane] = e1; ps[128 + lane] = e2;
        if (lane < 4) ps[192 + lane] = e3;
        float inv = 1.f / dn;
        float p0 = 0, p1 = 0, p2 = 0, p3 = 0;
        for (int s = 0; s < SS; s += 4){
          p0 += ps[s]     * V[(size_t)(s)     * 64 + lane];
          p1 += ps[s + 1] * V[(size_t)(s + 1) * 64 + lane];
          p2 += ps[s + 2] * V[(size_t)(s + 2) * 64 + lane];
          p3 += ps[s + 3] * V[(size_t)(s + 3) * 64 + lane];
        }
        sm[3328 + h * 64 + lane] = ((p0 + p1) + (p2 + p3)) * inv;
      }
      __syncthreads();
      // D: attnproj = ao @ Wo + bo  ->  A rows 0..511
      {
        int e = tid;
        float a0 = 0, a1 = 0, a2 = 0, a3 = 0;
        #pragma unroll 8
        for (int k = 0; k < EE; k += 4){
          a0 += sm[3328 + k]     * p.Wo[(size_t)(k)     * EE + e];
          a1 += sm[3328 + k + 1] * p.Wo[(size_t)(k + 1) * EE + e];
          a2 += sm[3328 + k + 2] * p.Wo[(size_t)(k + 2) * EE + e];
          a3 += sm[3328 + k + 3] * p.Wo[(size_t)(k + 3) * EE + e];
        }
        ast(&p.A[(size_t)e * 64 + b], p.bo[e] + ((a0 + a1) + (a2 + a3)));
      }
      // E: out-GEMV(t-1) — block-local so in LDS, Wout column-coalesced
      if (t > 0){
        #pragma unroll
        for (int half = 0; half < 2; half++){
          int n = tid + half * 512;
          if (n < OUTN){
            float a0 = 0, a1 = 0, a2 = 0, a3 = 0;
            #pragma unroll 8
            for (int k = 0; k < NSS; k += 4){
              a0 += sm[512 + k]     * p.Wout[(size_t)(k)     * OUTN + n];
              a1 += sm[512 + k + 1] * p.Wout[(size_t)(k + 1) * OUTN + n];
              a2 += sm[512 + k + 2] * p.Wout[(size_t)(k + 2) * OUTN + n];
              a3 += sm[512 + k + 3] * p.Wout[(size_t)(k + 3) * OUTN + n];
            }
            p.dout[((size_t)b * OUTN + n) * TT + (t - 1)] = p.bout[n] + ((a0 + a1) + (a2 + a3));
          }
        }
      }
    } else if (blk == 64){
      if (tid < 64){ ast(&p.psum[tid], 0.f); ast(&p.psq[tid], 0.f); }
    }
    gbar(arrive, release, ++g);

    // ========== P2: k-split synapse GEMM -> partials ==========
    {
      int ks = blk >> 5;          // 0..7
      int ct = blk & 31;          // 0..31
      int kr0 = ks * 320;
      // stage A-slice [320][64] into LDS (coherent reads, once per block)
      const float* Asrc = p.A + (size_t)kr0 * 64;
      for (int i0 = 0; i0 < 40; i0 += 8){
        float v[8];
        #pragma unroll
        for (int j = 0; j < 8; j++)
          v[j] = ald(&Asrc[(size_t)(i0 + j) * 512 + tid]);
        #pragma unroll
        for (int j = 0; j < 8; j++)
          sm[(i0 + j) * 512 + tid] = v[j];
      }
      __syncthreads();
      int cj0 = rfl(wv * 16);
      int colbase = (wv < 4) ? (ct * 64 + cj0) : (2048 + ct * 64 + (cj0 - 64));
      const float* W = p.Wsyn + colbase;
      float acc[16];
      #pragma unroll
      for (int i = 0; i < 16; i++) acc[i] = 0.f;
      for (int k = 0; k < 320; k++){
        float a = sm[k * 64 + lane];
        const float* wk = W + (size_t)(kr0 + k) * NSYN;
        #pragma unroll
        for (int i = 0; i < 16; i++) acc[i] += a * wk[i];
      }
      float* pp = p.part + ((size_t)ks * NSYN + colbase) * 64;
      #pragma unroll
      for (int i = 0; i < 16; i++) ast(&pp[(size_t)i * 64 + lane], acc[i]);
    }
    gbar(arrive, release, ++g);

    // ========== P3a: combine partials + GLU + psum atomicAdd (u stays in LDS) ==========
    {
      int ci = tid >> 6;          // 0..7
      int b = lane;
      int c0 = blk * 8;           // d-range start
      float lo = p.bsyn[c0 + ci], hi = p.bsyn[2048 + c0 + ci];
      float pl[8], ph[8];
      #pragma unroll
      for (int ks = 0; ks < 8; ks++){
        pl[ks] = ald(&p.part[((size_t)ks * NSYN + c0 + ci) * 64 + b]);
        ph[ks] = ald(&p.part[((size_t)ks * NSYN + 2048 + c0 + ci) * 64 + b]);
      }
      #pragma unroll
      for (int ks = 0; ks < 8; ks++){ lo += pl[ks]; hi += ph[ks]; }
      float u = lo * sigm(hi);
      sm[20480 + ci * 64 + b] = u;
      __syncthreads();
      if (tid < 64){
        float s = 0.f, q = 0.f;
        #pragma unroll
        for (int c = 0; c < 8; c++){
          float uu = sm[20480 + c * 64 + tid];
          s += uu; q += uu * uu;
        }
        atomicAdd(&p.psum[tid], s);
        atomicAdd(&p.psq[tid], q);
      }
    }
    gbar(arrive, release, ++g);

    // ========== P3b: LN finalize + per-neuron MLP (block = 8 d's) ==========
    {
      int d0 = blk * 8;
      // stage w1 slice
      for (int idx = tid; idx < 1600; idx += 512){
        float4 va = *reinterpret_cast<const float4*>(p.w1 + (size_t)idx * DD + d0);
        float4 vb = *reinterpret_cast<const float4*>(p.w1 + (size_t)idx * DD + d0 + 4);
        sm[0 * 1600 + idx] = va.x; sm[1 * 1600 + idx] = va.y;
        sm[2 * 1600 + idx] = va.z; sm[3 * 1600 + idx] = va.w;
        sm[4 * 1600 + idx] = vb.x; sm[5 * 1600 + idx] = vb.y;
        sm[6 * 1600 + idx] = vb.z; sm[7 * 1600 + idx] = vb.w;
      }
      float ts = ald(&p.psum[lane]);
      float tq = ald(&p.psq[lane]);
      float mean = ts * (1.f / DD);
      float var = tq * (1.f / DD) - mean * mean;
      float rsv = 1.f / sqrtf(var + 1e-5f);
      __syncthreads();
      int dd = rfl(wv);
      int d = d0 + dd;
      float u = sm[20480 + dd * 64 + lane];
      float snew = (u - mean) * rsv * p.gsyn[d] + p.bsn[d];
      int slot = t % MM;
      p.tr[((size_t)slot * DD + d) * 64 + lane] = snew;   // block-local ring
      float hp[64];
      #pragma unroll
      for (int h = 0; h < 64; h++) hp[h] = p.b1[(size_t)d * 64 + h];
      for (int j = 0; j < MM - 1; j++){
        int js = (t + 1 + j) % MM;
        float tv = p.tr[((size_t)js * DD + d) * 64 + lane];
        const float* wr = &sm[dd * 1600 + j * 64];
        #pragma unroll
        for (int h4 = 0; h4 < 16; h4++){
          float4 w = *reinterpret_cast<const float4*>(&wr[h4 * 4]);
          hp[h4 * 4 + 0] += tv * w.x;
          hp[h4 * 4 + 1] += tv * w.y;
          hp[h4 * 4 + 2] += tv * w.z;
          hp[h4 * 4 + 3] += tv * w.w;
        }
      }
      {
        const float* wr = &sm[dd * 1600 + 24 * 64];
        #pragma unroll
        for (int h4 = 0; h4 < 16; h4++){
          float4 w = *reinterpret_cast<const float4*>(&wr[h4 * 4]);
          hp[h4 * 4 + 0] += snew * w.x;
          hp[h4 * 4 + 1] += snew * w.y;
          hp[h4 * 4 + 2] += snew * w.z;
          hp[h4 * 4 + 3] += snew * w.w;
        }
      }
      float o0 = p.b2[(size_t)d * 2], o1 = p.b2[(size_t)d * 2 + 1];
      #pragma unroll
      for (int h2 = 0; h2 < HNN; h2++){
        float hh = hp[h2] * sigm(hp[h2 + HNN]);
        o0 += hh * p.w2[((size_t)(h2 * 2)) * DD + d];
        o1 += hh * p.w2[((size_t)(h2 * 2 + 1)) * DD + d];
      }
      ast(&p.act[(size_t)d * 64 + lane], o0 * sigm(o1));
    }
    gbar(arrive, release, ++g);
  }

  // ========== tail: sO(49) + SYNC output + out-GEMV(49), all block-local ==========
  if (blk < BB){
    const int b = blk;
    {
      int n = tid;
      float po = ald(&p.act[(size_t)p.iol[n] * 64 + b]) * ald(&p.act[(size_t)p.ior[n] * 64 + b]);
      float r2 = p.rO[n];
      float na2 = r2 * p.aO[(size_t)b * NSS + n] + po;
      float nb2 = r2 * p.bO[(size_t)b * NSS + n] + 1.f;
      float sv = na2 / sqrtf(nb2);
      sm[512 + n] = sv;
      p.dout[SYNC_OFF + (size_t)b * NSS + n] = sv;
    }
    __syncthreads();
    #pragma unroll
    for (int half = 0; half < 2; half++){
      int n = tid + half * 512;
      if (n < OUTN){
        float a0 = 0, a1 = 0, a2 = 0, a3 = 0;
        #pragma unroll 8
        for (int k = 0; k < NSS; k += 4){
          a0 += sm[512 + k]     * p.Wout[(size_t)(k)     * OUTN + n];
          a1 += sm[512 + k + 1] * p.Wout[(size_t)(k + 1) * OUTN + n];
          a2 += sm[512 + k + 2] * p.Wout[(size_t)(k + 2) * OUTN + n];
          a3 += sm[512 + k + 3] * p.Wout[(size_t)(k + 3) * OUTN + n];
        }
        p.dout[((size_t)b * OUTN + n) * TT + (TT - 1)] = p.bout[n] + ((a0 + a1) + (a2 + a3));
      }
    }
  }
}

// ---------------- certainty from stored predictions ----------------
__global__ __launch_bounds__(256) void cert_kernel(float* __restrict__ dout)
{
  int blk = blockIdx.x;
  int b = blk / TT, t = blk % TT;
  int tid = threadIdx.x;
  __shared__ float red[256];
  float vals[4];
  float mx = -1e30f;
  #pragma unroll
  for (int i = 0; i < 4; i++){
    int n = tid + i * 256;
    float v = (n < OUTN) ? dout[((size_t)b * OUTN + n) * TT + t] : -1e30f;
    vals[i] = v; mx = fmaxf(mx, v);
  }
  red[tid] = mx; __syncthreads();
  for (int st = 128; st > 0; st >>= 1){ if (tid < st) red[tid] = fmaxf(red[tid], red[tid + st]); __syncthreads(); }
  mx = red[0]; __syncthreads();
  float z = 0.f, s1 = 0.f;
  #pragma unroll
  for (int i = 0; i < 4; i++){
    int n = tid + i * 256;
    if (n < OUTN){
      float e = expf(vals[i] - mx);
      z += e; s1 += e * (vals[i] - mx);
    }
  }
  red[tid] = z; __syncthreads();
  for (int st = 128; st > 0; st >>= 1){ if (tid < st) red[tid] += red[tid + st]; __syncthreads(); }
  z = red[0]; __syncthreads();
  red[tid] = s1; __syncthreads();
  for (int st = 128; st > 0; st >>= 1){ if (tid < st) red[tid] += red[tid + st]; __syncthreads(); }
  s1 = red[0];
  if (tid == 0){
    float ne = (logf(z) - s1 / z) * (1.f / logf(1000.f));
    dout[CERT_OFF + ((size_t)b * 2 + 0) * TT + t] = ne;
    dout[CERT_OFF + ((size_t)b * 2 + 1) * TT + t] = 1.f - ne;
  }
}

extern "C" void kernel_launch(void* const* d_in, const int* in_sizes, int n_in,
                              void* d_out, int out_size, void* d_ws, size_t ws_size,
                              hipStream_t stream)
{
  const float* x    = (const float*)d_in[0];
  const float* Wkv  = (const float*)d_in[1];
  const float* bkv  = (const float*)d_in[2];
  const float* gkv  = (const float*)d_in[3];
  const float* bkv2 = (const float*)d_in[4];
  const float* Wq   = (const float*)d_in[5];
  const float* bq   = (const float*)d_in[6];
  const float* Wqa  = (const float*)d_in[7];
  const float* bqa  = (const float*)d_in[8];
  const float* Wka  = (const float*)d_in[9];
  const float* bka  = (const float*)d_in[10];
  const float* Wva  = (const float*)d_in[11];
  const float* bva  = (const float*)d_in[12];
  const float* Wo   = (const float*)d_in[13];
  const float* bo   = (const float*)d_in[14];
  const float* Wsyn = (const float*)d_in[15];
  const float* bsyn = (const float*)d_in[16];
  const float* gsyn = (const float*)d_in[17];
  const float* bsn  = (const float*)d_in[18];
  const float* w1   = (const float*)d_in[19];
  const float* b1   = (const float*)d_in[20];
  const float* w2   = (const float*)d_in[21];
  const float* b2   = (const float*)d_in[22];
  const float* sact = (const float*)d_in[23];
  const float* strc = (const float*)d_in[24];
  const float* dcA  = (const float*)d_in[25];
  const float* dcO  = (const float*)d_in[26];
  const float* Wout = (const float*)d_in[27];
  const float* bout = (const float*)d_in[28];
  const int* ial = (const int*)d_in[29];
  const int* iar = (const int*)d_in[30];
  const int* iol = (const int*)d_in[31];
  const int* ior = (const int*)d_in[32];

  char* ws = (char*)d_ws;
  float* khT  = (float*)(ws + 0);          // 25,690,112
  float* vh   = (float*)(ws + 25690112);   // 25,690,112 -> 51,380,224
  float* B0   = (float*)(ws + 51380224);   // 12,845,056 (precompute scratch)
  float* B1   = (float*)(ws + 64225280);   // 12,845,056 -> 77,070,336
  // step-time region (overlays B0/B1):
  float* tr    = (float*)(ws + 51380224);  // 13,107,200 -> 64,487,424
  float* A     = (float*)(ws + 64487424);  // 655,360 (attnproj rows 0..511 | act rows 512..2559)
  float* act   = A + 512 * 64;
  float* part  = (float*)(ws + 65142784);  // 8,388,608 -> 73,531,392
  float* aA    = (float*)(ws + 73531392);  // 131,072
  float* bA    = (float*)(ws + 73662464);  // 131,072
  float* aO    = (float*)(ws + 73793536);  // 131,072
  float* bO    = (float*)(ws + 73924608);  // 131,072 -> 74,055,680
  float* Wqq   = (float*)(ws + 74055680);  // 1,048,576 -> 75,104,256
  float* bqqb  = (float*)(ws + 75104256);  // 2,048
  float* rA    = (float*)(ws + 75106304);  // 2,048
  float* rO    = (float*)(ws + 75108352);  // 2,048
  float* psum  = (float*)(ws + 75110400);  // 512
  float* psq   = (float*)(ws + 75110912);  // 512
  unsigned* flags = (unsigned*)(ws + 75111424); // 2,048 -> 75,113,472
  float* dout = (float*)d_out;

  for (int c = 0; c < 2; c++){
    const float* xc = x + (size_t)c * 6272 * EE;
    sgemm<0><<<dim3(98, 8), 256, 0, stream>>>(xc, Wkv, bkv, B0, 6272, EE, EE, 0);
    ln_rows_kernel<<<6272, 256, 0, stream>>>(B0, gkv, bkv2, B1);
    sgemm<3><<<dim3(98, 8), 256, 0, stream>>>(B1, Wka, bka, khT, 6272, EE, EE, c * 6272);
    sgemm<1><<<dim3(98, 8), 256, 0, stream>>>(B1, Wva, bva, vh, 6272, EE, EE, c * 6272);
  }
  sgemm<0><<<dim3(8, 8), 256, 0, stream>>>(Wq, Wqa, nullptr, Wqq, EE, EE, EE, 0);
  bqq_kernel<<<1, 512, 0, stream>>>(bq, Wqa, bqa, bqqb);
  prep_decay<<<1, 512, 0, stream>>>(dcA, dcO, rA, rO);
  init_kernel<<<512, 256, 0, stream>>>(sact, strc, iol, ior, act, tr, aA, bA, aO, bO,
                                       psum, psq, flags);

  CtmParams prm;
  prm.khT = khT; prm.vh = vh; prm.Wqq = Wqq; prm.bqq = bqqb;
  prm.Wo = Wo; prm.bo = bo; prm.Wsyn = Wsyn; prm.bsyn = bsyn;
  prm.gsyn = gsyn; prm.bsn = bsn;
  prm.w1 = w1; prm.b1 = b1; prm.w2 = w2; prm.b2 = b2;
  prm.Wout = Wout; prm.bout = bout; prm.rA = rA; prm.rO = rO;
  prm.ial = ial; prm.iar = iar; prm.iol = iol; prm.ior = ior;
  prm.A = A; prm.act = act; prm.part = part;
  prm.psum = psum; prm.psq = psq;
  prm.aA = aA; prm.bA = bA; prm.aO = aO; prm.bO = bO;
  prm.tr = tr; prm.dout = dout; prm.flags = flags;

  void* kargs[1] = { &prm };
  hipLaunchCooperativeKernel((const void*)ctm_persist, dim3(256), dim3(512), kargs, 0, stream);

  cert_kernel<<<BB * TT, 256, 0, stream>>>(dout);
}

// Round 12
// 8242.885 us; speedup vs baseline: 2.8533x; 2.8533x over previous
//
#include <hip/hip_runtime.h>

#define BB 64
#define SS 196
#define EE 512
#define DD 2048
#define MM 25
#define HNN 32
#define NHH 8
#define TT 50
#define NSS 512
#define OUTN 1000
#define HDD 64
#define KSYN 2560
#define NSYN 4096

#define CERT_OFF 3200000
#define SYNC_OFF 3206400

__device__ __forceinline__ float sigm(float x){ return 1.f / (1.f + expf(-x)); }
__device__ __forceinline__ int rfl(int x){ return __builtin_amdgcn_readfirstlane(x); }

// ---------------- f32 GEMM (precompute) ----------------
// LAYOUT 0: row-major. 1: vh permute ((b*8+h)*196+s)*64+d. 3: khT ((b*8+h)*64+d)*196+s.
template<int LAYOUT>
__global__ __launch_bounds__(256) void sgemm(
    const float* __restrict__ Ag, const float* __restrict__ Wg,
    const float* __restrict__ bias, float* __restrict__ Cg,
    int Mg, int Ng, int Kg, int ro)
{
  __shared__ float As[16][68];
  __shared__ float Bs[16][68];
  int t = threadIdx.x;
  int bm = blockIdx.x * 64, bn = blockIdx.y * 64;
  int ty = t >> 4, tx = t & 15;
  int atm = t >> 2, atk = (t & 3) * 4;
  int bkk = t >> 4, bnn = (t & 15) * 4;
  float c[4][4] = {};
  for (int k0 = 0; k0 < Kg; k0 += 16){
    float4 av = *reinterpret_cast<const float4*>(Ag + (size_t)(bm + atm) * Kg + k0 + atk);
    As[atk][atm] = av.x; As[atk + 1][atm] = av.y;
    As[atk + 2][atm] = av.z; As[atk + 3][atm] = av.w;
    float4 bv = *reinterpret_cast<const float4*>(Wg + (size_t)(k0 + bkk) * Ng + bn + bnn);
    *reinterpret_cast<float4*>(&Bs[bkk][bnn]) = bv;
    __syncthreads();
    #pragma unroll
    for (int k = 0; k < 16; k++){
      float4 a = *reinterpret_cast<const float4*>(&As[k][ty * 4]);
      float4 b = *reinterpret_cast<const float4*>(&Bs[k][tx * 4]);
      c[0][0] += a.x * b.x; c[0][1] += a.x * b.y; c[0][2] += a.x * b.z; c[0][3] += a.x * b.w;
      c[1][0] += a.y * b.x; c[1][1] += a.y * b.y; c[1][2] += a.y * b.z; c[1][3] += a.y * b.w;
      c[2][0] += a.z * b.x; c[2][1] += a.z * b.y; c[2][2] += a.z * b.z; c[2][3] += a.z * b.w;
      c[3][0] += a.w * b.x; c[3][1] += a.w * b.y; c[3][2] += a.w * b.z; c[3][3] += a.w * b.w;
    }
    __syncthreads();
  }
  #pragma unroll
  for (int j = 0; j < 4; j++){
    int col = bn + tx * 4 + j;
    float bvv = bias ? bias[col] : 0.f;
    #pragma unroll
    for (int i = 0; i < 4; i++){
      int row = bm + ty * 4 + i;
      float v = c[i][j] + bvv;
      if (LAYOUT == 0){
        Cg[(size_t)row * Ng + col] = v;
      } else {
        int tok = ro + row;
        int b = tok / SS, s = tok - b * SS;
        int h = col >> 6, dh = col & 63;
        if (LAYOUT == 1) Cg[(((size_t)b * NHH + h) * SS + s) * HDD + dh] = v;
        else             Cg[(((size_t)b * NHH + h) * HDD + dh) * SS + s] = v;
      }
    }
  }
}

// ---------------- LayerNorm rows ----------------
__global__ __launch_bounds__(256) void ln_rows_kernel(const float* __restrict__ y,
    const float* __restrict__ g, const float* __restrict__ bb,
    float* __restrict__ outf)
{
  int r = blockIdx.x, t = threadIdx.x;
  __shared__ float red[256];
  const float* row = y + (size_t)r * EE;
  float v0 = row[t], v1 = row[t + 256];
  red[t] = v0 + v1; __syncthreads();
  for (int st = 128; st > 0; st >>= 1){ if (t < st) red[t] += red[t + st]; __syncthreads(); }
  float mean = red[0] * (1.f / EE); __syncthreads();
  float d0 = v0 - mean, d1 = v1 - mean;
  red[t] = d0 * d0 + d1 * d1; __syncthreads();
  for (int st = 128; st > 0; st >>= 1){ if (t < st) red[t] += red[t + st]; __syncthreads(); }
  float rs = 1.f / sqrtf(red[0] * (1.f / EE) + 1e-5f);
  float* orow = outf + (size_t)r * EE;
  orow[t] = d0 * rs * g[t] + bb[t];
  orow[t + 256] = d1 * rs * g[t + 256] + bb[t + 256];
}

// ---------------- bqq = bq @ Wqa + bqa ----------------
__global__ __launch_bounds__(512) void bqq_kernel(const float* __restrict__ bq,
    const float* __restrict__ Wqa, const float* __restrict__ bqa, float* __restrict__ bqq)
{
  __shared__ float s[EE];
  int t = threadIdx.x;
  s[t] = bq[t]; __syncthreads();
  float a0 = 0, a1 = 0, a2 = 0, a3 = 0;
  #pragma unroll 8
  for (int k = 0; k < EE; k += 4){
    a0 += s[k]     * Wqa[(size_t)(k)     * EE + t];
    a1 += s[k + 1] * Wqa[(size_t)(k + 1) * EE + t];
    a2 += s[k + 2] * Wqa[(size_t)(k + 2) * EE + t];
    a3 += s[k + 3] * Wqa[(size_t)(k + 3) * EE + t];
  }
  bqq[t] = bqa[t] + ((a0 + a1) + (a2 + a3));
}

// ---------------- decay -> rate ----------------
__global__ __launch_bounds__(512) void prep_decay(const float* __restrict__ dcA,
    const float* __restrict__ dcO, float* __restrict__ rA, float* __restrict__ rO)
{
  int t = threadIdx.x;
  rA[t] = expf(-fminf(fmaxf(dcA[t], 0.f), 15.f));
  rO[t] = expf(-fminf(fmaxf(dcO[t], 0.f), 15.f));
}

// ---------------- init state (+psum parity buffers) ----------------
__global__ __launch_bounds__(256) void init_kernel(const float* __restrict__ sa,
    const float* __restrict__ strace,
    const int* __restrict__ ol, const int* __restrict__ orr,
    float* __restrict__ act, float* __restrict__ tr,
    float* __restrict__ aA, float* __restrict__ bA,
    float* __restrict__ aO, float* __restrict__ bO,
    float* __restrict__ psum, float* __restrict__ psq)
{
  int tid = blockIdx.x * 256 + threadIdx.x;
  if (tid < 128){ psum[tid] = 0.f; psq[tid] = 0.f; }
  int b = tid >> 11, d = tid & 2047;
  act[(size_t)d * 64 + b] = sa[d];
  for (int m = 0; m < MM; m++)
    tr[((size_t)m * DD + d) * 64 + b] = strace[d * MM + m];
  if (tid < BB * NSS){
    int n = tid & (NSS - 1);
    int b2 = tid >> 9;
    aO[(size_t)b2 * NSS + n] = sa[ol[n]] * sa[orr[n]];
    bO[(size_t)b2 * NSS + n] = 1.f;
    aA[(size_t)b2 * NSS + n] = 0.f;
    bA[(size_t)b2 * NSS + n] = 0.f;
  }
}

// ---------------- K1: front (64 blocks = batch b) ----------------
__global__ __launch_bounds__(512) void k_front(
    const float* __restrict__ khT, const float* __restrict__ vh,
    const float* __restrict__ Wqq, const float* __restrict__ bqq,
    const float* __restrict__ Wo, const float* __restrict__ bo,
    const float* __restrict__ rA, const float* __restrict__ rO,
    const int* __restrict__ ial, const int* __restrict__ iar,
    const int* __restrict__ iol, const int* __restrict__ ior,
    float* __restrict__ aA, float* __restrict__ bA,
    float* __restrict__ aO, float* __restrict__ bO,
    const float* __restrict__ act, float* __restrict__ A,
    float* __restrict__ so_g, float* __restrict__ dout, int t)
{
  __shared__ float sm[4096];
  const int tid = threadIdx.x, b = blockIdx.x;
  const int lane = tid & 63, wv = tid >> 6;
  {
    int n = tid;
    if (t < TT){
      float pa = act[(size_t)ial[n] * 64 + b] * act[(size_t)iar[n] * 64 + b];
      float r = rA[n];
      float na = r * aA[(size_t)b * NSS + n] + pa;
      float nb = r * bA[(size_t)b * NSS + n] + 1.f;
      aA[(size_t)b * NSS + n] = na; bA[(size_t)b * NSS + n] = nb;
      sm[n] = na / sqrtf(nb);
    }
    if (t > 0){
      float po = act[(size_t)iol[n] * 64 + b] * act[(size_t)ior[n] * 64 + b];
      float r2 = rO[n];
      float na2 = r2 * aO[(size_t)b * NSS + n] + po;
      float nb2 = r2 * bO[(size_t)b * NSS + n] + 1.f;
      aO[(size_t)b * NSS + n] = na2; bO[(size_t)b * NSS + n] = nb2;
      float sv = na2 / sqrtf(nb2);
      so_g[(size_t)b * NSS + n] = sv;
      if (t == TT) dout[SYNC_OFF + (size_t)b * NSS + n] = sv;
    }
  }
  if (t >= TT) return;
  __syncthreads();
  // q2 = sA @ Wqq + bqq
  {
    int e = tid;
    float a0 = 0, a1 = 0, a2 = 0, a3 = 0;
    #pragma unroll 8
    for (int k = 0; k < EE; k += 4){
      a0 += sm[k]     * Wqq[(size_t)(k)     * EE + e];
      a1 += sm[k + 1] * Wqq[(size_t)(k + 1) * EE + e];
      a2 += sm[k + 2] * Wqq[(size_t)(k + 2) * EE + e];
      a3 += sm[k + 3] * Wqq[(size_t)(k + 3) * EE + e];
    }
    sm[1024 + e] = bqq[e] + ((a0 + a1) + (a2 + a3));
  }
  __syncthreads();
  // attention (wave = head)
  {
    int h = wv;
    int u = b * NHH + h;
    const float* K = khT + (size_t)u * HDD * SS;
    const float* V = vh + (size_t)u * SS * HDD;
    float c0 = 0, c1 = 0, c2 = 0, c3 = 0;
    for (int d2 = 0; d2 < HDD; d2++){
      float qd = sm[1024 + h * 64 + d2];
      const float* Kr = K + (size_t)d2 * SS;
      c0 += qd * Kr[lane];
      c1 += qd * Kr[64 + lane];
      c2 += qd * Kr[128 + lane];
      c3 += qd * Kr[192 + lane];
    }
    float s0 = c0 * 0.125f, s1 = c1 * 0.125f, s2 = c2 * 0.125f;
    float s3 = (lane < 4) ? c3 * 0.125f : -1e30f;
    float mx = fmaxf(fmaxf(s0, s1), fmaxf(s2, s3));
    #pragma unroll
    for (int off = 32; off > 0; off >>= 1)
      mx = fmaxf(mx, __shfl_xor(mx, off, 64));
    float e0 = expf(s0 - mx), e1 = expf(s1 - mx), e2 = expf(s2 - mx);
    float e3 = (lane < 4) ? expf(s3 - mx) : 0.f;
    float dn = e0 + e1 + e2 + e3;
    #pragma unroll
    for (int off = 32; off > 0; off >>= 1)
      dn += __shfl_xor(dn, off, 64);
    float* ps = sm + 1536 + h * 224;
    ps[lane] = e0; ps[64 + lane] = e1; ps[128 + lane] = e2;
    if (lane < 4) ps[192 + lane] = e3;
    float inv = 1.f / dn;
    float p0 = 0, p1 = 0, p2 = 0, p3 = 0;
    for (int s = 0; s < SS; s += 4){
      p0 += ps[s]     * V[(size_t)(s)     * 64 + lane];
      p1 += ps[s + 1] * V[(size_t)(s + 1) * 64 + lane];
      p2 += ps[s + 2] * V[(size_t)(s + 2) * 64 + lane];
      p3 += ps[s + 3] * V[(size_t)(s + 3) * 64 + lane];
    }
    sm[3328 + h * 64 + lane] = ((p0 + p1) + (p2 + p3)) * inv;
  }
  __syncthreads();
  // attnproj = ao @ Wo + bo -> A rows 0..511
  {
    int e = tid;
    float a0 = 0, a1 = 0, a2 = 0, a3 = 0;
    #pragma unroll 8
    for (int k = 0; k < EE; k += 4){
      a0 += sm[3328 + k]     * Wo[(size_t)(k)     * EE + e];
      a1 += sm[3328 + k + 1] * Wo[(size_t)(k + 1) * EE + e];
      a2 += sm[3328 + k + 2] * Wo[(size_t)(k + 2) * EE + e];
      a3 += sm[3328 + k + 3] * Wo[(size_t)(k + 3) * EE + e];
    }
    A[(size_t)e * 64 + b] = bo[e] + ((a0 + a1) + (a2 + a3));
  }
}

// ---------------- K2: synapse GEMM (blocks 0..255) + out-GEMV(t-1) (blocks 256..319) ----------------
__global__ __launch_bounds__(512) void k_synout(
    const float* __restrict__ A, const float* __restrict__ Wsyn,
    const float* __restrict__ bsyn, const float* __restrict__ Wout,
    const float* __restrict__ bout, const float* __restrict__ so_g,
    float* __restrict__ glupre, float* __restrict__ psum, float* __restrict__ psq,
    float* __restrict__ dout, int t)
{
  __shared__ float sm[8704];
  const int tid = threadIdx.x, blk = blockIdx.x;
  const int lane = tid & 63, wv = tid >> 6;
  const int par = t & 1;
  if (blk < 256){
    if (t >= TT) return;
    int c0 = blk * 8;
    const float* Wl = Wsyn + c0;
    const float* Wh = Wsyn + 2048 + c0;
    float acc[16];
    #pragma unroll
    for (int i = 0; i < 16; i++) acc[i] = 0.f;
    int kb = rfl(wv * 320);
    #pragma unroll 4
    for (int k = kb; k < kb + 320; k++){
      float a = A[(size_t)k * 64 + lane];
      const float* wl = Wl + (size_t)k * NSYN;
      const float* wh = Wh + (size_t)k * NSYN;
      #pragma unroll
      for (int ci = 0; ci < 8; ci++){
        acc[ci]     += a * wl[ci];
        acc[8 + ci] += a * wh[ci];
      }
    }
    #pragma unroll
    for (int i = 0; i < 16; i++) sm[wv * 1024 + i * 64 + lane] = acc[i];
    __syncthreads();
    {
      int ci = tid >> 6;
      int b = lane;
      float x0 = 0.f, x1 = 0.f;
      #pragma unroll
      for (int w = 0; w < 8; w++){
        x0 += sm[w * 1024 + ci * 64 + b];
        x1 += sm[w * 1024 + (8 + ci) * 64 + b];
      }
      x0 += bsyn[c0 + ci]; x1 += bsyn[2048 + c0 + ci];
      float u = x0 * sigm(x1);
      glupre[(size_t)(c0 + ci) * 64 + b] = u;
      sm[8192 + ci * 64 + b] = u;
    }
    __syncthreads();
    if (tid < 64){
      float s = 0.f, q = 0.f;
      #pragma unroll
      for (int c = 0; c < 8; c++){
        float uu = sm[8192 + c * 64 + tid];
        s += uu; q += uu * uu;
      }
      atomicAdd(&psum[par * 64 + tid], s);
      atomicAdd(&psq[par * 64 + tid], q);
    }
  } else {
    if (t == 0) return;
    int b = blk - 256;
    for (int k = tid; k < NSS; k += 512) sm[k] = so_g[(size_t)b * NSS + k];
    __syncthreads();
    #pragma unroll
    for (int half = 0; half < 2; half++){
      int n = tid + half * 512;
      if (n < OUTN){
        float a0 = 0, a1 = 0, a2 = 0, a3 = 0;
        #pragma unroll 8
        for (int k = 0; k < NSS; k += 4){
          a0 += sm[k]     * Wout[(size_t)(k)     * OUTN + n];
          a1 += sm[k + 1] * Wout[(size_t)(k + 1) * OUTN + n];
          a2 += sm[k + 2] * Wout[(size_t)(k + 2) * OUTN + n];
          a3 += sm[k + 3] * Wout[(size_t)(k + 3) * OUTN + n];
        }
        dout[((size_t)b * OUTN + n) * TT + (t - 1)] = bout[n] + ((a0 + a1) + (a2 + a3));
      }
    }
  }
}

// ---------------- K3: LN finalize + per-neuron MLP (256 blocks = 8 d's each) ----------------
__global__ __launch_bounds__(512) void k_nlm(
    const float* __restrict__ glupre, float* __restrict__ psum, float* __restrict__ psq,
    const float* __restrict__ gsyn, const float* __restrict__ bsn,
    const float* __restrict__ w1, const float* __restrict__ b1,
    const float* __restrict__ w2, const float* __restrict__ b2,
    float* __restrict__ tr, float* __restrict__ act, int t)
{
  __shared__ float sm[12800];
  const int tid = threadIdx.x, blk = blockIdx.x;
  const int lane = tid & 63, wv = tid >> 6;
  const int par = t & 1;
  if (blk == 0 && tid < 64){
    psum[(par ^ 1) * 64 + tid] = 0.f;
    psq[(par ^ 1) * 64 + tid] = 0.f;
  }
  int d0 = blk * 8;
  for (int idx = tid; idx < 1600; idx += 512){
    float4 va = *reinterpret_cast<const float4*>(w1 + (size_t)idx * DD + d0);
    float4 vb = *reinterpret_cast<const float4*>(w1 + (size_t)idx * DD + d0 + 4);
    sm[0 * 1600 + idx] = va.x; sm[1 * 1600 + idx] = va.y;
    sm[2 * 1600 + idx] = va.z; sm[3 * 1600 + idx] = va.w;
    sm[4 * 1600 + idx] = vb.x; sm[5 * 1600 + idx] = vb.y;
    sm[6 * 1600 + idx] = vb.z; sm[7 * 1600 + idx] = vb.w;
  }
  float ts = psum[par * 64 + lane];
  float tq = psq[par * 64 + lane];
  float mean = ts * (1.f / DD);
  float var = tq * (1.f / DD) - mean * mean;
  float rsv = 1.f / sqrtf(var + 1e-5f);
  __syncthreads();
  int dd = rfl(wv);
  int d = d0 + dd;
  float u = glupre[(size_t)d * 64 + lane];
  float snew = (u - mean) * rsv * gsyn[d] + bsn[d];
  int slot = t % MM;
  tr[((size_t)slot * DD + d) * 64 + lane] = snew;
  float hp[64];
  #pragma unroll
  for (int h = 0; h < 64; h++) hp[h] = b1[(size_t)d * 64 + h];
  for (int j = 0; j < MM - 1; j++){
    int js = (t + 1 + j) % MM;
    float tv = tr[((size_t)js * DD + d) * 64 + lane];
    const float* wr = &sm[dd * 1600 + j * 64];
    #pragma unroll
    for (int h4 = 0; h4 < 16; h4++){
      float4 w = *reinterpret_cast<const float4*>(&wr[h4 * 4]);
      hp[h4 * 4 + 0] += tv * w.x;
      hp[h4 * 4 + 1] += tv * w.y;
      hp[h4 * 4 + 2] += tv * w.z;
      hp[h4 * 4 + 3] += tv * w.w;
    }
  }
  {
    const float* wr = &sm[dd * 1600 + 24 * 64];
    #pragma unroll
    for (int h4 = 0; h4 < 16; h4++){
      float4 w = *reinterpret_cast<const float4*>(&wr[h4 * 4]);
      hp[h4 * 4 + 0] += snew * w.x;
      hp[h4 * 4 + 1] += snew * w.y;
      hp[h4 * 4 + 2] += snew * w.z;
      hp[h4 * 4 + 3] += snew * w.w;
    }
  }
  float o0 = b2[(size_t)d * 2], o1 = b2[(size_t)d * 2 + 1];
  #pragma unroll
  for (int h2 = 0; h2 < HNN; h2++){
    float hh = hp[h2] * sigm(hp[h2 + HNN]);
    o0 += hh * w2[((size_t)(h2 * 2)) * DD + d];
    o1 += hh * w2[((size_t)(h2 * 2 + 1)) * DD + d];
  }
  act[(size_t)d * 64 + lane] = o0 * sigm(o1);
}

// ---------------- certainty from stored predictions ----------------
__global__ __launch_bounds__(256) void cert_kernel(float* __restrict__ dout)
{
  int blk = blockIdx.x;
  int b = blk / TT, t = blk % TT;
  int tid = threadIdx.x;
  __shared__ float red[256];
  float vals[4];
  float mx = -1e30f;
  #pragma unroll
  for (int i = 0; i < 4; i++){
    int n = tid + i * 256;
    float v = (n < OUTN) ? dout[((size_t)b * OUTN + n) * TT + t] : -1e30f;
    vals[i] = v; mx = fmaxf(mx, v);
  }
  red[tid] = mx; __syncthreads();
  for (int st = 128; st > 0; st >>= 1){ if (tid < st) red[tid] = fmaxf(red[tid], red[tid + st]); __syncthreads(); }
  mx = red[0]; __syncthreads();
  float z = 0.f, s1 = 0.f;
  #pragma unroll
  for (int i = 0; i < 4; i++){
    int n = tid + i * 256;
    if (n < OUTN){
      float e = expf(vals[i] - mx);
      z += e; s1 += e * (vals[i] - mx);
    }
  }
  red[tid] = z; __syncthreads();
  for (int st = 128; st > 0; st >>= 1){ if (tid < st) red[tid] += red[tid + st]; __syncthreads(); }
  z = red[0]; __syncthreads();
  red[tid] = s1; __syncthreads();
  for (int st = 128; st > 0; st >>= 1){ if (tid < st) red[tid] += red[tid + st]; __syncthreads(); }
  s1 = red[0];
  if (tid == 0){
    float ne = (logf(z) - s1 / z) * (1.f / logf(1000.f));
    dout[CERT_OFF + ((size_t)b * 2 + 0) * TT + t] = ne;
    dout[CERT_OFF + ((size_t)b * 2 + 1) * TT + t] = 1.f - ne;
  }
}

extern "C" void kernel_launch(void* const* d_in, const int* in_sizes, int n_in,
                              void* d_out, int out_size, void* d_ws, size_t ws_size,
                              hipStream_t stream)
{
  const float* x    = (const float*)d_in[0];
  const float* Wkv  = (const float*)d_in[1];
  const float* bkv  = (const float*)d_in[2];
  const float* gkv  = (const float*)d_in[3];
  const float* bkv2 = (const float*)d_in[4];
  const float* Wq   = (const float*)d_in[5];
  const float* bq   = (const float*)d_in[6];
  const float* Wqa  = (const float*)d_in[7];
  const float* bqa  = (const float*)d_in[8];
  const float* Wka  = (const float*)d_in[9];
  const float* bka  = (const float*)d_in[10];
  const float* Wva  = (const float*)d_in[11];
  const float* bva  = (const float*)d_in[12];
  const float* Wo   = (const float*)d_in[13];
  const float* bo   = (const float*)d_in[14];
  const float* Wsyn = (const float*)d_in[15];
  const float* bsyn = (const float*)d_in[16];
  const float* gsyn = (const float*)d_in[17];
  const float* bsn  = (const float*)d_in[18];
  const float* w1   = (const float*)d_in[19];
  const float* b1   = (const float*)d_in[20];
  const float* w2   = (const float*)d_in[21];
  const float* b2   = (const float*)d_in[22];
  const float* sact = (const float*)d_in[23];
  const float* strc = (const float*)d_in[24];
  const float* dcA  = (const float*)d_in[25];
  const float* dcO  = (const float*)d_in[26];
  const float* Wout = (const float*)d_in[27];
  const float* bout = (const float*)d_in[28];
  const int* ial = (const int*)d_in[29];
  const int* iar = (const int*)d_in[30];
  const int* iol = (const int*)d_in[31];
  const int* ior = (const int*)d_in[32];

  char* ws = (char*)d_ws;
  float* khT  = (float*)(ws + 0);          // 25,690,112
  float* vh   = (float*)(ws + 25690112);   // 25,690,112 -> 51,380,224
  float* B0   = (float*)(ws + 51380224);   // precompute scratch
  float* B1   = (float*)(ws + 64225280);   //   -> 77,070,336
  // step-time region (overlays B0/B1):
  float* tr    = (float*)(ws + 51380224);  // 13,107,200 -> 64,487,424
  float* A     = (float*)(ws + 64487424);  // 655,360 (attnproj 512 rows | act 2048 rows)
  float* act   = A + 512 * 64;             //   -> 65,142,784
  float* glupre= (float*)(ws + 65142784);  // 524,288 -> 65,667,072
  float* aA    = (float*)(ws + 65667072);  // 131,072
  float* bA    = (float*)(ws + 65798144);  // 131,072
  float* aO    = (float*)(ws + 65929216);  // 131,072
  float* bO    = (float*)(ws + 66060288);  // 131,072 -> 66,191,360
  float* so_g  = (float*)(ws + 66191360);  // 131,072 -> 66,322,432
  float* Wqq   = (float*)(ws + 66322432);  // 1,048,576 -> 67,371,008
  float* bqqb  = (float*)(ws + 67371008);  // 2,048
  float* rA    = (float*)(ws + 67373056);  // 2,048
  float* rO    = (float*)(ws + 67375104);  // 2,048
  float* psum  = (float*)(ws + 67377152);  // 512 (2 parities x 64)
  float* psq   = (float*)(ws + 67377664);  // 512
  float* dout = (float*)d_out;

  for (int c = 0; c < 2; c++){
    const float* xc = x + (size_t)c * 6272 * EE;
    sgemm<0><<<dim3(98, 8), 256, 0, stream>>>(xc, Wkv, bkv, B0, 6272, EE, EE, 0);
    ln_rows_kernel<<<6272, 256, 0, stream>>>(B0, gkv, bkv2, B1);
    sgemm<3><<<dim3(98, 8), 256, 0, stream>>>(B1, Wka, bka, khT, 6272, EE, EE, c * 6272);
    sgemm<1><<<dim3(98, 8), 256, 0, stream>>>(B1, Wva, bva, vh, 6272, EE, EE, c * 6272);
  }
  sgemm<0><<<dim3(8, 8), 256, 0, stream>>>(Wq, Wqa, nullptr, Wqq, EE, EE, EE, 0);
  bqq_kernel<<<1, 512, 0, stream>>>(bq, Wqa, bqa, bqqb);
  prep_decay<<<1, 512, 0, stream>>>(dcA, dcO, rA, rO);
  init_kernel<<<512, 256, 0, stream>>>(sact, strc, iol, ior, act, tr, aA, bA, aO, bO,
                                       psum, psq);

  for (int t = 0; t < TT; t++){
    k_front<<<64, 512, 0, stream>>>(khT, vh, Wqq, bqqb, Wo, bo, rA, rO,
                                    ial, iar, iol, ior, aA, bA, aO, bO,
                                    act, A, so_g, dout, t);
    k_synout<<<320, 512, 0, stream>>>(A, Wsyn, bsyn, Wout, bout, so_g,
                                      glupre, psum, psq, dout, t);
    k_nlm<<<256, 512, 0, stream>>>(glupre, psum, psq, gsyn, bsn,
                                   w1, b1, w2, b2, tr, act, t);
  }
  // tail: sO(49) + SYNC write, then out-GEMV(49)
  k_front<<<64, 512, 0, stream>>>(khT, vh, Wqq, bqqb, Wo, bo, rA, rO,
                                  ial, iar, iol, ior, aA, bA, aO, bO,
                                  act, A, so_g, dout, TT);
  k_synout<<<320, 512, 0, stream>>>(A, Wsyn, bsyn, Wout, bout, so_g,
                                    glupre, psum, psq, dout, TT);
  cert_kernel<<<BB * TT, 256, 0, stream>>>(dout);
}

// Round 13
// 8072.934 us; speedup vs baseline: 2.9133x; 1.0211x over previous
//
#include <hip/hip_runtime.h>

#define BB 64
#define SS 196
#define EE 512
#define DD 2048
#define MM 25
#define HNN 32
#define NHH 8
#define TT 50
#define NSS 512
#define OUTN 1000
#define HDD 64
#define KSYN 2560
#define NSYN 4096

#define CERT_OFF 3200000
#define SYNC_OFF 3206400

__device__ __forceinline__ float sigm(float x){ return 1.f / (1.f + expf(-x)); }
__device__ __forceinline__ int rfl(int x){ return __builtin_amdgcn_readfirstlane(x); }

// ---------------- f32 GEMM (precompute) ----------------
// LAYOUT 0: row-major. 1: vh permute ((b*8+h)*196+s)*64+d. 3: khT ((b*8+h)*64+d)*196+s.
template<int LAYOUT>
__global__ __launch_bounds__(256) void sgemm(
    const float* __restrict__ Ag, const float* __restrict__ Wg,
    const float* __restrict__ bias, float* __restrict__ Cg,
    int Mg, int Ng, int Kg, int ro)
{
  __shared__ float As[16][68];
  __shared__ float Bs[16][68];
  int t = threadIdx.x;
  int bm = blockIdx.x * 64, bn = blockIdx.y * 64;
  int ty = t >> 4, tx = t & 15;
  int atm = t >> 2, atk = (t & 3) * 4;
  int bkk = t >> 4, bnn = (t & 15) * 4;
  float c[4][4] = {};
  for (int k0 = 0; k0 < Kg; k0 += 16){
    float4 av = *reinterpret_cast<const float4*>(Ag + (size_t)(bm + atm) * Kg + k0 + atk);
    As[atk][atm] = av.x; As[atk + 1][atm] = av.y;
    As[atk + 2][atm] = av.z; As[atk + 3][atm] = av.w;
    float4 bv = *reinterpret_cast<const float4*>(Wg + (size_t)(k0 + bkk) * Ng + bn + bnn);
    *reinterpret_cast<float4*>(&Bs[bkk][bnn]) = bv;
    __syncthreads();
    #pragma unroll
    for (int k = 0; k < 16; k++){
      float4 a = *reinterpret_cast<const float4*>(&As[k][ty * 4]);
      float4 b = *reinterpret_cast<const float4*>(&Bs[k][tx * 4]);
      c[0][0] += a.x * b.x; c[0][1] += a.x * b.y; c[0][2] += a.x * b.z; c[0][3] += a.x * b.w;
      c[1][0] += a.y * b.x; c[1][1] += a.y * b.y; c[1][2] += a.y * b.z; c[1][3] += a.y * b.w;
      c[2][0] += a.z * b.x; c[2][1] += a.z * b.y; c[2][2] += a.z * b.z; c[2][3] += a.z * b.w;
      c[3][0] += a.w * b.x; c[3][1] += a.w * b.y; c[3][2] += a.w * b.z; c[3][3] += a.w * b.w;
    }
    __syncthreads();
  }
  #pragma unroll
  for (int j = 0; j < 4; j++){
    int col = bn + tx * 4 + j;
    float bvv = bias ? bias[col] : 0.f;
    #pragma unroll
    for (int i = 0; i < 4; i++){
      int row = bm + ty * 4 + i;
      float v = c[i][j] + bvv;
      if (LAYOUT == 0){
        Cg[(size_t)row * Ng + col] = v;
      } else {
        int tok = ro + row;
        int b = tok / SS, s = tok - b * SS;
        int h = col >> 6, dh = col & 63;
        if (LAYOUT == 1) Cg[(((size_t)b * NHH + h) * SS + s) * HDD + dh] = v;
        else             Cg[(((size_t)b * NHH + h) * HDD + dh) * SS + s] = v;
      }
    }
  }
}

// ---------------- LayerNorm rows ----------------
__global__ __launch_bounds__(256) void ln_rows_kernel(const float* __restrict__ y,
    const float* __restrict__ g, const float* __restrict__ bb,
    float* __restrict__ outf)
{
  int r = blockIdx.x, t = threadIdx.x;
  __shared__ float red[256];
  const float* row = y + (size_t)r * EE;
  float v0 = row[t], v1 = row[t + 256];
  red[t] = v0 + v1; __syncthreads();
  for (int st = 128; st > 0; st >>= 1){ if (t < st) red[t] += red[t + st]; __syncthreads(); }
  float mean = red[0] * (1.f / EE); __syncthreads();
  float d0 = v0 - mean, d1 = v1 - mean;
  red[t] = d0 * d0 + d1 * d1; __syncthreads();
  for (int st = 128; st > 0; st >>= 1){ if (t < st) red[t] += red[t + st]; __syncthreads(); }
  float rs = 1.f / sqrtf(red[0] * (1.f / EE) + 1e-5f);
  float* orow = outf + (size_t)r * EE;
  orow[t] = d0 * rs * g[t] + bb[t];
  orow[t + 256] = d1 * rs * g[t + 256] + bb[t + 256];
}

// ---------------- bqq = bq @ Wqa + bqa ----------------
__global__ __launch_bounds__(512) void bqq_kernel(const float* __restrict__ bq,
    const float* __restrict__ Wqa, const float* __restrict__ bqa, float* __restrict__ bqq)
{
  __shared__ float s[EE];
  int t = threadIdx.x;
  s[t] = bq[t]; __syncthreads();
  float a0 = 0, a1 = 0, a2 = 0, a3 = 0;
  #pragma unroll 8
  for (int k = 0; k < EE; k += 4){
    a0 += s[k]     * Wqa[(size_t)(k)     * EE + t];
    a1 += s[k + 1] * Wqa[(size_t)(k + 1) * EE + t];
    a2 += s[k + 2] * Wqa[(size_t)(k + 2) * EE + t];
    a3 += s[k + 3] * Wqa[(size_t)(k + 3) * EE + t];
  }
  bqq[t] = bqa[t] + ((a0 + a1) + (a2 + a3));
}

// ---------------- decay -> rate ----------------
__global__ __launch_bounds__(512) void prep_decay(const float* __restrict__ dcA,
    const float* __restrict__ dcO, float* __restrict__ rA, float* __restrict__ rO)
{
  int t = threadIdx.x;
  rA[t] = expf(-fminf(fmaxf(dcA[t], 0.f), 15.f));
  rO[t] = expf(-fminf(fmaxf(dcO[t], 0.f), 15.f));
}

// ---------------- Wsyn pair-interleave: W2[k][2c+h] = Wsyn[k][c + 2048h] ----------------
__global__ __launch_bounds__(256) void permute_wsyn(const float* __restrict__ Wsyn,
    float* __restrict__ W2)
{
  int k = blockIdx.x;
  const float* src = Wsyn + (size_t)k * NSYN;
  float* dst = W2 + (size_t)k * NSYN;
  for (int c = threadIdx.x; c < 2048; c += 256){
    float2 v; v.x = src[c]; v.y = src[2048 + c];
    *reinterpret_cast<float2*>(&dst[2 * c]) = v;
  }
}

// ---------------- init state (+psum parity buffers) ----------------
__global__ __launch_bounds__(256) void init_kernel(const float* __restrict__ sa,
    const float* __restrict__ strace,
    const int* __restrict__ ol, const int* __restrict__ orr,
    float* __restrict__ act, float* __restrict__ tr,
    float* __restrict__ aA, float* __restrict__ bA,
    float* __restrict__ aO, float* __restrict__ bO,
    float* __restrict__ psum, float* __restrict__ psq)
{
  int tid = blockIdx.x * 256 + threadIdx.x;
  if (tid < 128){ psum[tid] = 0.f; psq[tid] = 0.f; }
  int b = tid >> 11, d = tid & 2047;
  act[(size_t)d * 64 + b] = sa[d];
  for (int m = 0; m < MM; m++)
    tr[((size_t)m * DD + d) * 64 + b] = strace[d * MM + m];
  if (tid < BB * NSS){
    int n = tid & (NSS - 1);
    int b2 = tid >> 9;
    aO[(size_t)b2 * NSS + n] = sa[ol[n]] * sa[orr[n]];
    bO[(size_t)b2 * NSS + n] = 1.f;
    aA[(size_t)b2 * NSS + n] = 0.f;
    bA[(size_t)b2 * NSS + n] = 0.f;
  }
}

// ---------------- K1: front (64 blocks = batch b) ----------------
__global__ __launch_bounds__(512) void k_front(
    const float* __restrict__ khT, const float* __restrict__ vh,
    const float* __restrict__ Wqq, const float* __restrict__ bqq,
    const float* __restrict__ Wo, const float* __restrict__ bo,
    const float* __restrict__ rA, const float* __restrict__ rO,
    const int* __restrict__ ial, const int* __restrict__ iar,
    const int* __restrict__ iol, const int* __restrict__ ior,
    float* __restrict__ aA, float* __restrict__ bA,
    float* __restrict__ aO, float* __restrict__ bO,
    const float* __restrict__ act, float* __restrict__ A,
    float* __restrict__ so_g, float* __restrict__ dout, int t)
{
  __shared__ float sm[4096];
  const int tid = threadIdx.x, b = blockIdx.x;
  const int lane = tid & 63, wv = tid >> 6;
  {
    int n = tid;
    if (t < TT){
      float pa = act[(size_t)ial[n] * 64 + b] * act[(size_t)iar[n] * 64 + b];
      float r = rA[n];
      float na = r * aA[(size_t)b * NSS + n] + pa;
      float nb = r * bA[(size_t)b * NSS + n] + 1.f;
      aA[(size_t)b * NSS + n] = na; bA[(size_t)b * NSS + n] = nb;
      sm[n] = na / sqrtf(nb);
    }
    if (t > 0){
      float po = act[(size_t)iol[n] * 64 + b] * act[(size_t)ior[n] * 64 + b];
      float r2 = rO[n];
      float na2 = r2 * aO[(size_t)b * NSS + n] + po;
      float nb2 = r2 * bO[(size_t)b * NSS + n] + 1.f;
      aO[(size_t)b * NSS + n] = na2; bO[(size_t)b * NSS + n] = nb2;
      float sv = na2 / sqrtf(nb2);
      so_g[(size_t)b * NSS + n] = sv;
      if (t == TT) dout[SYNC_OFF + (size_t)b * NSS + n] = sv;
    }
  }
  if (t >= TT) return;
  __syncthreads();
  {
    int e = tid;
    float a0 = 0, a1 = 0, a2 = 0, a3 = 0;
    #pragma unroll 8
    for (int k = 0; k < EE; k += 4){
      a0 += sm[k]     * Wqq[(size_t)(k)     * EE + e];
      a1 += sm[k + 1] * Wqq[(size_t)(k + 1) * EE + e];
      a2 += sm[k + 2] * Wqq[(size_t)(k + 2) * EE + e];
      a3 += sm[k + 3] * Wqq[(size_t)(k + 3) * EE + e];
    }
    sm[1024 + e] = bqq[e] + ((a0 + a1) + (a2 + a3));
  }
  __syncthreads();
  {
    int h = wv;
    int u = b * NHH + h;
    const float* K = khT + (size_t)u * HDD * SS;
    const float* V = vh + (size_t)u * SS * HDD;
    float c0 = 0, c1 = 0, c2 = 0, c3 = 0;
    for (int d2 = 0; d2 < HDD; d2++){
      float qd = sm[1024 + h * 64 + d2];
      const float* Kr = K + (size_t)d2 * SS;
      c0 += qd * Kr[lane];
      c1 += qd * Kr[64 + lane];
      c2 += qd * Kr[128 + lane];
      c3 += qd * Kr[192 + lane];
    }
    float s0 = c0 * 0.125f, s1 = c1 * 0.125f, s2 = c2 * 0.125f;
    float s3 = (lane < 4) ? c3 * 0.125f : -1e30f;
    float mx = fmaxf(fmaxf(s0, s1), fmaxf(s2, s3));
    #pragma unroll
    for (int off = 32; off > 0; off >>= 1)
      mx = fmaxf(mx, __shfl_xor(mx, off, 64));
    float e0 = expf(s0 - mx), e1 = expf(s1 - mx), e2 = expf(s2 - mx);
    float e3 = (lane < 4) ? expf(s3 - mx) : 0.f;
    float dn = e0 + e1 + e2 + e3;
    #pragma unroll
    for (int off = 32; off > 0; off >>= 1)
      dn += __shfl_xor(dn, off, 64);
    float* ps = sm + 1536 + h * 224;
    ps[lane] = e0; ps[64 + lane] = e1; ps[128 + lane] = e2;
    if (lane < 4) ps[192 + lane] = e3;
    float inv = 1.f / dn;
    float p0 = 0, p1 = 0, p2 = 0, p3 = 0;
    for (int s = 0; s < SS; s += 4){
      p0 += ps[s]     * V[(size_t)(s)     * 64 + lane];
      p1 += ps[s + 1] * V[(size_t)(s + 1) * 64 + lane];
      p2 += ps[s + 2] * V[(size_t)(s + 2) * 64 + lane];
      p3 += ps[s + 3] * V[(size_t)(s + 3) * 64 + lane];
    }
    sm[3328 + h * 64 + lane] = ((p0 + p1) + (p2 + p3)) * inv;
  }
  __syncthreads();
  {
    int e = tid;
    float a0 = 0, a1 = 0, a2 = 0, a3 = 0;
    #pragma unroll 8
    for (int k = 0; k < EE; k += 4){
      a0 += sm[3328 + k]     * Wo[(size_t)(k)     * EE + e];
      a1 += sm[3328 + k + 1] * Wo[(size_t)(k + 1) * EE + e];
      a2 += sm[3328 + k + 2] * Wo[(size_t)(k + 2) * EE + e];
      a3 += sm[3328 + k + 3] * Wo[(size_t)(k + 3) * EE + e];
    }
    A[(size_t)e * 64 + b] = bo[e] + ((a0 + a1) + (a2 + a3));
  }
}

// ---------------- K2 fast: interleaved-Wsyn GEMM (0..255) + out-GEMV (256..319) ----------------
__global__ __launch_bounds__(512) void k_syn2(
    const float* __restrict__ A, const float* __restrict__ W2,
    const float* __restrict__ bsyn, const float* __restrict__ Wout,
    const float* __restrict__ bout, const float* __restrict__ so_g,
    float* __restrict__ glupre, float* __restrict__ psum, float* __restrict__ psq,
    float* __restrict__ dout, int t)
{
  __shared__ float sm[8704];
  const int tid = threadIdx.x, blk = blockIdx.x;
  const int lane = tid & 63, wv = tid >> 6;
  const int par = t & 1;
  if (blk < 256){
    if (t >= TT) return;
    int c0 = blk * 8;
    int cc = 2 * c0;                       // 16 contiguous floats per k-row
    float acc[16];
    #pragma unroll
    for (int i = 0; i < 16; i++) acc[i] = 0.f;
    int kb = rfl(wv * 320);
    #pragma unroll 2
    for (int k = kb; k < kb + 320; k++){
      float a = A[(size_t)k * 64 + lane];
      const float4* w = reinterpret_cast<const float4*>(W2 + (size_t)k * NSYN + cc);
      float4 w0 = w[0], w1 = w[1], w2 = w[2], w3 = w[3];
      acc[0]  += a * w0.x; acc[8]  += a * w0.y;
      acc[1]  += a * w0.z; acc[9]  += a * w0.w;
      acc[2]  += a * w1.x; acc[10] += a * w1.y;
      acc[3]  += a * w1.z; acc[11] += a * w1.w;
      acc[4]  += a * w2.x; acc[12] += a * w2.y;
      acc[5]  += a * w2.z; acc[13] += a * w2.w;
      acc[6]  += a * w3.x; acc[14] += a * w3.y;
      acc[7]  += a * w3.z; acc[15] += a * w3.w;
    }
    #pragma unroll
    for (int i = 0; i < 16; i++) sm[wv * 1024 + i * 64 + lane] = acc[i];
    __syncthreads();
    {
      int ci = tid >> 6;
      int b = lane;
      float x0 = 0.f, x1 = 0.f;
      #pragma unroll
      for (int w = 0; w < 8; w++){
        x0 += sm[w * 1024 + ci * 64 + b];
        x1 += sm[w * 1024 + (8 + ci) * 64 + b];
      }
      x0 += bsyn[c0 + ci]; x1 += bsyn[2048 + c0 + ci];
      float u = x0 * sigm(x1);
      glupre[(size_t)(c0 + ci) * 64 + b] = u;
      sm[8192 + ci * 64 + b] = u;
    }
    __syncthreads();
    if (tid < 64){
      float s = 0.f, q = 0.f;
      #pragma unroll
      for (int c = 0; c < 8; c++){
        float uu = sm[8192 + c * 64 + tid];
        s += uu; q += uu * uu;
      }
      atomicAdd(&psum[par * 64 + tid], s);
      atomicAdd(&psq[par * 64 + tid], q);
    }
  } else {
    if (t == 0) return;
    int b = blk - 256;
    for (int k = tid; k < NSS; k += 512) sm[k] = so_g[(size_t)b * NSS + k];
    __syncthreads();
    #pragma unroll
    for (int half = 0; half < 2; half++){
      int n = tid + half * 512;
      if (n < OUTN){
        float a0 = 0, a1 = 0, a2 = 0, a3 = 0;
        #pragma unroll 8
        for (int k = 0; k < NSS; k += 4){
          a0 += sm[k]     * Wout[(size_t)(k)     * OUTN + n];
          a1 += sm[k + 1] * Wout[(size_t)(k + 1) * OUTN + n];
          a2 += sm[k + 2] * Wout[(size_t)(k + 2) * OUTN + n];
          a3 += sm[k + 3] * Wout[(size_t)(k + 3) * OUTN + n];
        }
        dout[((size_t)b * OUTN + n) * TT + (t - 1)] = bout[n] + ((a0 + a1) + (a2 + a3));
      }
    }
  }
}

// ---------------- K2 fallback: original column-read synapse GEMM ----------------
__global__ __launch_bounds__(512) void k_synout(
    const float* __restrict__ A, const float* __restrict__ Wsyn,
    const float* __restrict__ bsyn, const float* __restrict__ Wout,
    const float* __restrict__ bout, const float* __restrict__ so_g,
    float* __restrict__ glupre, float* __restrict__ psum, float* __restrict__ psq,
    float* __restrict__ dout, int t)
{
  __shared__ float sm[8704];
  const int tid = threadIdx.x, blk = blockIdx.x;
  const int lane = tid & 63, wv = tid >> 6;
  const int par = t & 1;
  if (blk < 256){
    if (t >= TT) return;
    int c0 = blk * 8;
    const float* Wl = Wsyn + c0;
    const float* Wh = Wsyn + 2048 + c0;
    float acc[16];
    #pragma unroll
    for (int i = 0; i < 16; i++) acc[i] = 0.f;
    int kb = rfl(wv * 320);
    #pragma unroll 4
    for (int k = kb; k < kb + 320; k++){
      float a = A[(size_t)k * 64 + lane];
      const float* wl = Wl + (size_t)k * NSYN;
      const float* wh = Wh + (size_t)k * NSYN;
      #pragma unroll
      for (int ci = 0; ci < 8; ci++){
        acc[ci]     += a * wl[ci];
        acc[8 + ci] += a * wh[ci];
      }
    }
    #pragma unroll
    for (int i = 0; i < 16; i++) sm[wv * 1024 + i * 64 + lane] = acc[i];
    __syncthreads();
    {
      int ci = tid >> 6;
      int b = lane;
      float x0 = 0.f, x1 = 0.f;
      #pragma unroll
      for (int w = 0; w < 8; w++){
        x0 += sm[w * 1024 + ci * 64 + b];
        x1 += sm[w * 1024 + (8 + ci) * 64 + b];
      }
      x0 += bsyn[c0 + ci]; x1 += bsyn[2048 + c0 + ci];
      float u = x0 * sigm(x1);
      glupre[(size_t)(c0 + ci) * 64 + b] = u;
      sm[8192 + ci * 64 + b] = u;
    }
    __syncthreads();
    if (tid < 64){
      float s = 0.f, q = 0.f;
      #pragma unroll
      for (int c = 0; c < 8; c++){
        float uu = sm[8192 + c * 64 + tid];
        s += uu; q += uu * uu;
      }
      atomicAdd(&psum[par * 64 + tid], s);
      atomicAdd(&psq[par * 64 + tid], q);
    }
  } else {
    if (t == 0) return;
    int b = blk - 256;
    for (int k = tid; k < NSS; k += 512) sm[k] = so_g[(size_t)b * NSS + k];
    __syncthreads();
    #pragma unroll
    for (int half = 0; half < 2; half++){
      int n = tid + half * 512;
      if (n < OUTN){
        float a0 = 0, a1 = 0, a2 = 0, a3 = 0;
        #pragma unroll 8
        for (int k = 0; k < NSS; k += 4){
          a0 += sm[k]     * Wout[(size_t)(k)     * OUTN + n];
          a1 += sm[k + 1] * Wout[(size_t)(k + 1) * OUTN + n];
          a2 += sm[k + 2] * Wout[(size_t)(k + 2) * OUTN + n];
          a3 += sm[k + 3] * Wout[(size_t)(k + 3) * OUTN + n];
        }
        dout[((size_t)b * OUTN + n) * TT + (t - 1)] = bout[n] + ((a0 + a1) + (a2 + a3));
      }
    }
  }
}

// ---------------- K3: LN finalize + per-neuron MLP (256 blocks = 8 d's each) ----------------
__global__ __launch_bounds__(512) void k_nlm(
    const float* __restrict__ glupre, float* __restrict__ psum, float* __restrict__ psq,
    const float* __restrict__ gsyn, const float* __restrict__ bsn,
    const float* __restrict__ w1, const float* __restrict__ b1,
    const float* __restrict__ w2, const float* __restrict__ b2,
    float* __restrict__ tr, float* __restrict__ act, int t)
{
  __shared__ float sm[12800];
  const int tid = threadIdx.x, blk = blockIdx.x;
  const int lane = tid & 63, wv = tid >> 6;
  const int par = t & 1;
  if (blk == 0 && tid < 64){
    psum[(par ^ 1) * 64 + tid] = 0.f;
    psq[(par ^ 1) * 64 + tid] = 0.f;
  }
  int d0 = blk * 8;
  for (int idx = tid; idx < 1600; idx += 512){
    float4 va = *reinterpret_cast<const float4*>(w1 + (size_t)idx * DD + d0);
    float4 vb = *reinterpret_cast<const float4*>(w1 + (size_t)idx * DD + d0 + 4);
    sm[0 * 1600 + idx] = va.x; sm[1 * 1600 + idx] = va.y;
    sm[2 * 1600 + idx] = va.z; sm[3 * 1600 + idx] = va.w;
    sm[4 * 1600 + idx] = vb.x; sm[5 * 1600 + idx] = vb.y;
    sm[6 * 1600 + idx] = vb.z; sm[7 * 1600 + idx] = vb.w;
  }
  float ts = psum[par * 64 + lane];
  float tq = psq[par * 64 + lane];
  float mean = ts * (1.f / DD);
  float var = tq * (1.f / DD) - mean * mean;
  float rsv = 1.f / sqrtf(var + 1e-5f);
  __syncthreads();
  int dd = rfl(wv);
  int d = d0 + dd;
  float u = glupre[(size_t)d * 64 + lane];
  float snew = (u - mean) * rsv * gsyn[d] + bsn[d];
  int slot = t % MM;
  tr[((size_t)slot * DD + d) * 64 + lane] = snew;
  float hp[64];
  #pragma unroll
  for (int h = 0; h < 64; h++) hp[h] = b1[(size_t)d * 64 + h];
  for (int j = 0; j < MM - 1; j++){
    int js = (t + 1 + j) % MM;
    float tv = tr[((size_t)js * DD + d) * 64 + lane];
    const float* wr = &sm[dd * 1600 + j * 64];
    #pragma unroll
    for (int h4 = 0; h4 < 16; h4++){
      float4 w = *reinterpret_cast<const float4*>(&wr[h4 * 4]);
      hp[h4 * 4 + 0] += tv * w.x;
      hp[h4 * 4 + 1] += tv * w.y;
      hp[h4 * 4 + 2] += tv * w.z;
      hp[h4 * 4 + 3] += tv * w.w;
    }
  }
  {
    const float* wr = &sm[dd * 1600 + 24 * 64];
    #pragma unroll
    for (int h4 = 0; h4 < 16; h4++){
      float4 w = *reinterpret_cast<const float4*>(&wr[h4 * 4]);
      hp[h4 * 4 + 0] += snew * w.x;
      hp[h4 * 4 + 1] += snew * w.y;
      hp[h4 * 4 + 2] += snew * w.z;
      hp[h4 * 4 + 3] += snew * w.w;
    }
  }
  float o0 = b2[(size_t)d * 2], o1 = b2[(size_t)d * 2 + 1];
  #pragma unroll
  for (int h2 = 0; h2 < HNN; h2++){
    float hh = hp[h2] * sigm(hp[h2 + HNN]);
    o0 += hh * w2[((size_t)(h2 * 2)) * DD + d];
    o1 += hh * w2[((size_t)(h2 * 2 + 1)) * DD + d];
  }
  act[(size_t)d * 64 + lane] = o0 * sigm(o1);
}

// ---------------- certainty from stored predictions ----------------
__global__ __launch_bounds__(256) void cert_kernel(float* __restrict__ dout)
{
  int blk = blockIdx.x;
  int b = blk / TT, t = blk % TT;
  int tid = threadIdx.x;
  __shared__ float red[256];
  float vals[4];
  float mx = -1e30f;
  #pragma unroll
  for (int i = 0; i < 4; i++){
    int n = tid + i * 256;
    float v = (n < OUTN) ? dout[((size_t)b * OUTN + n) * TT + t] : -1e30f;
    vals[i] = v; mx = fmaxf(mx, v);
  }
  red[tid] = mx; __syncthreads();
  for (int st = 128; st > 0; st >>= 1){ if (tid < st) red[tid] = fmaxf(red[tid], red[tid + st]); __syncthreads(); }
  mx = red[0]; __syncthreads();
  float z = 0.f, s1 = 0.f;
  #pragma unroll
  for (int i = 0; i < 4; i++){
    int n = tid + i * 256;
    if (n < OUTN){
      float e = expf(vals[i] - mx);
      z += e; s1 += e * (vals[i] - mx);
    }
  }
  red[tid] = z; __syncthreads();
  for (int st = 128; st > 0; st >>= 1){ if (tid < st) red[tid] += red[tid + st]; __syncthreads(); }
  z = red[0]; __syncthreads();
  red[tid] = s1; __syncthreads();
  for (int st = 128; st > 0; st >>= 1){ if (tid < st) red[tid] += red[tid + st]; __syncthreads(); }
  s1 = red[0];
  if (tid == 0){
    float ne = (logf(z) - s1 / z) * (1.f / logf(1000.f));
    dout[CERT_OFF + ((size_t)b * 2 + 0) * TT + t] = ne;
    dout[CERT_OFF + ((size_t)b * 2 + 1) * TT + t] = 1.f - ne;
  }
}

extern "C" void kernel_launch(void* const* d_in, const int* in_sizes, int n_in,
                              void* d_out, int out_size, void* d_ws, size_t ws_size,
                              hipStream_t stream)
{
  const float* x    = (const float*)d_in[0];
  const float* Wkv  = (const float*)d_in[1];
  const float* bkv  = (const float*)d_in[2];
  const float* gkv  = (const float*)d_in[3];
  const float* bkv2 = (const float*)d_in[4];
  const float* Wq   = (const float*)d_in[5];
  const float* bq   = (const float*)d_in[6];
  const float* Wqa  = (const float*)d_in[7];
  const float* bqa  = (const float*)d_in[8];
  const float* Wka  = (const float*)d_in[9];
  const float* bka  = (const float*)d_in[10];
  const float* Wva  = (const float*)d_in[11];
  const float* bva  = (const float*)d_in[12];
  const float* Wo   = (const float*)d_in[13];
  const float* bo   = (const float*)d_in[14];
  const float* Wsyn = (const float*)d_in[15];
  const float* bsyn = (const float*)d_in[16];
  const float* gsyn = (const float*)d_in[17];
  const float* bsn  = (const float*)d_in[18];
  const float* w1   = (const float*)d_in[19];
  const float* b1   = (const float*)d_in[20];
  const float* w2   = (const float*)d_in[21];
  const float* b2   = (const float*)d_in[22];
  const float* sact = (const float*)d_in[23];
  const float* strc = (const float*)d_in[24];
  const float* dcA  = (const float*)d_in[25];
  const float* dcO  = (const float*)d_in[26];
  const float* Wout = (const float*)d_in[27];
  const float* bout = (const float*)d_in[28];
  const int* ial = (const int*)d_in[29];
  const int* iar = (const int*)d_in[30];
  const int* iol = (const int*)d_in[31];
  const int* ior = (const int*)d_in[32];

  char* ws = (char*)d_ws;
  float* khT  = (float*)(ws + 0);          // 25,690,112
  float* vh   = (float*)(ws + 25690112);   // 25,690,112 -> 51,380,224
  float* B0   = (float*)(ws + 51380224);   // precompute scratch
  float* B1   = (float*)(ws + 64225280);   //   -> 77,070,336
  // step-time region (overlays B0/B1):
  float* tr    = (float*)(ws + 51380224);  // 13,107,200 -> 64,487,424
  float* A     = (float*)(ws + 64487424);  // 655,360 (attnproj 512 rows | act 2048 rows)
  float* act   = A + 512 * 64;             //   -> 65,142,784
  float* glupre= (float*)(ws + 65142784);  // 524,288 -> 65,667,072
  float* aA    = (float*)(ws + 65667072);  // 131,072
  float* bA    = (float*)(ws + 65798144);  // 131,072
  float* aO    = (float*)(ws + 65929216);  // 131,072
  float* bO    = (float*)(ws + 66060288);  // 131,072 -> 66,191,360
  float* so_g  = (float*)(ws + 66191360);  // 131,072 -> 66,322,432
  float* Wqq   = (float*)(ws + 66322432);  // 1,048,576 -> 67,371,008
  float* bqqb  = (float*)(ws + 67371008);  // 2,048
  float* rA    = (float*)(ws + 67373056);  // 2,048
  float* rO    = (float*)(ws + 67375104);  // 2,048
  float* psum  = (float*)(ws + 67377152);  // 512 (2 parities x 64)
  float* psq   = (float*)(ws + 67377664);  // 512
  float* W2    = (float*)(ws + 77070336);  // 41,943,040 -> 119,013,376 (fast path only)
  const size_t WS_NEED_FAST = 119013376;
  const bool fast = (ws_size >= WS_NEED_FAST);
  float* dout = (float*)d_out;

  for (int c = 0; c < 2; c++){
    const float* xc = x + (size_t)c * 6272 * EE;
    sgemm<0><<<dim3(98, 8), 256, 0, stream>>>(xc, Wkv, bkv, B0, 6272, EE, EE, 0);
    ln_rows_kernel<<<6272, 256, 0, stream>>>(B0, gkv, bkv2, B1);
    sgemm<3><<<dim3(98, 8), 256, 0, stream>>>(B1, Wka, bka, khT, 6272, EE, EE, c * 6272);
    sgemm<1><<<dim3(98, 8), 256, 0, stream>>>(B1, Wva, bva, vh, 6272, EE, EE, c * 6272);
  }
  sgemm<0><<<dim3(8, 8), 256, 0, stream>>>(Wq, Wqa, nullptr, Wqq, EE, EE, EE, 0);
  bqq_kernel<<<1, 512, 0, stream>>>(bq, Wqa, bqa, bqqb);
  prep_decay<<<1, 512, 0, stream>>>(dcA, dcO, rA, rO);
  if (fast) permute_wsyn<<<KSYN, 256, 0, stream>>>(Wsyn, W2);
  init_kernel<<<512, 256, 0, stream>>>(sact, strc, iol, ior, act, tr, aA, bA, aO, bO,
                                       psum, psq);

  for (int t = 0; t < TT; t++){
    k_front<<<64, 512, 0, stream>>>(khT, vh, Wqq, bqqb, Wo, bo, rA, rO,
                                    ial, iar, iol, ior, aA, bA, aO, bO,
                                    act, A, so_g, dout, t);
    if (fast)
      k_syn2<<<320, 512, 0, stream>>>(A, W2, bsyn, Wout, bout, so_g,
                                      glupre, psum, psq, dout, t);
    else
      k_synout<<<320, 512, 0, stream>>>(A, Wsyn, bsyn, Wout, bout, so_g,
                                        glupre, psum, psq, dout, t);
    k_nlm<<<256, 512, 0, stream>>>(glupre, psum, psq, gsyn, bsn,
                                   w1, b1, w2, b2, tr, act, t);
  }
  // tail: sO(49) + SYNC write, then out-GEMV(49)
  k_front<<<64, 512, 0, stream>>>(khT, vh, Wqq, bqqb, Wo, bo, rA, rO,
                                  ial, iar, iol, ior, aA, bA, aO, bO,
                                  act, A, so_g, dout, TT);
  if (fast)
    k_syn2<<<320, 512, 0, stream>>>(A, W2, bsyn, Wout, bout, so_g,
                                    glupre, psum, psq, dout, TT);
  else
    k_synout<<<320, 512, 0, stream>>>(A, Wsyn, bsyn, Wout, bout, so_g,
                                      glupre, psum, psq, dout, TT);
  cert_kernel<<<BB * TT, 256, 0, stream>>>(dout);
}

// Round 15
// 6571.035 us; speedup vs baseline: 3.5792x; 1.2286x over previous
//
#include <hip/hip_runtime.h>

#define BB 64
#define SS 196
#define EE 512
#define DD 2048
#define MM 25
#define HNN 32
#define NHH 8
#define TT 50
#define NSS 512
#define OUTN 1000
#define HDD 64
#define KSYN 2560
#define NSYN 4096

#define CERT_OFF 3200000
#define SYNC_OFF 3206400

__device__ __forceinline__ float sigm(float x){ return 1.f / (1.f + expf(-x)); }
__device__ __forceinline__ int rfl(int x){ return __builtin_amdgcn_readfirstlane(x); }

// ---------------- f32 GEMM (precompute) ----------------
// LAYOUT 0: row-major. 1: vh permute ((b*8+h)*196+s)*64+d. 3: khT ((b*8+h)*64+d)*196+s.
template<int LAYOUT>
__global__ __launch_bounds__(256) void sgemm(
    const float* __restrict__ Ag, const float* __restrict__ Wg,
    const float* __restrict__ bias, float* __restrict__ Cg,
    int Mg, int Ng, int Kg, int ro)
{
  __shared__ float As[16][68];
  __shared__ float Bs[16][68];
  int t = threadIdx.x;
  int bm = blockIdx.x * 64, bn = blockIdx.y * 64;
  int ty = t >> 4, tx = t & 15;
  int atm = t >> 2, atk = (t & 3) * 4;
  int bkk = t >> 4, bnn = (t & 15) * 4;
  float c[4][4] = {};
  for (int k0 = 0; k0 < Kg; k0 += 16){
    float4 av = *reinterpret_cast<const float4*>(Ag + (size_t)(bm + atm) * Kg + k0 + atk);
    As[atk][atm] = av.x; As[atk + 1][atm] = av.y;
    As[atk + 2][atm] = av.z; As[atk + 3][atm] = av.w;
    float4 bv = *reinterpret_cast<const float4*>(Wg + (size_t)(k0 + bkk) * Ng + bn + bnn);
    *reinterpret_cast<float4*>(&Bs[bkk][bnn]) = bv;
    __syncthreads();
    #pragma unroll
    for (int k = 0; k < 16; k++){
      float4 a = *reinterpret_cast<const float4*>(&As[k][ty * 4]);
      float4 b = *reinterpret_cast<const float4*>(&Bs[k][tx * 4]);
      c[0][0] += a.x * b.x; c[0][1] += a.x * b.y; c[0][2] += a.x * b.z; c[0][3] += a.x * b.w;
      c[1][0] += a.y * b.x; c[1][1] += a.y * b.y; c[1][2] += a.y * b.z; c[1][3] += a.y * b.w;
      c[2][0] += a.z * b.x; c[2][1] += a.z * b.y; c[2][2] += a.z * b.z; c[2][3] += a.z * b.w;
      c[3][0] += a.w * b.x; c[3][1] += a.w * b.y; c[3][2] += a.w * b.z; c[3][3] += a.w * b.w;
    }
    __syncthreads();
  }
  #pragma unroll
  for (int j = 0; j < 4; j++){
    int col = bn + tx * 4 + j;
    float bvv = bias ? bias[col] : 0.f;
    #pragma unroll
    for (int i = 0; i < 4; i++){
      int row = bm + ty * 4 + i;
      float v = c[i][j] + bvv;
      if (LAYOUT == 0){
        Cg[(size_t)row * Ng + col] = v;
      } else {
        int tok = ro + row;
        int b = tok / SS, s = tok - b * SS;
        int h = col >> 6, dh = col & 63;
        if (LAYOUT == 1) Cg[(((size_t)b * NHH + h) * SS + s) * HDD + dh] = v;
        else             Cg[(((size_t)b * NHH + h) * HDD + dh) * SS + s] = v;
      }
    }
  }
}

// ---------------- LayerNorm rows ----------------
__global__ __launch_bounds__(256) void ln_rows_kernel(const float* __restrict__ y,
    const float* __restrict__ g, const float* __restrict__ bb,
    float* __restrict__ outf)
{
  int r = blockIdx.x, t = threadIdx.x;
  __shared__ float red[256];
  const float* row = y + (size_t)r * EE;
  float v0 = row[t], v1 = row[t + 256];
  red[t] = v0 + v1; __syncthreads();
  for (int st = 128; st > 0; st >>= 1){ if (t < st) red[t] += red[t + st]; __syncthreads(); }
  float mean = red[0] * (1.f / EE); __syncthreads();
  float d0 = v0 - mean, d1 = v1 - mean;
  red[t] = d0 * d0 + d1 * d1; __syncthreads();
  for (int st = 128; st > 0; st >>= 1){ if (t < st) red[t] += red[t + st]; __syncthreads(); }
  float rs = 1.f / sqrtf(red[0] * (1.f / EE) + 1e-5f);
  float* orow = outf + (size_t)r * EE;
  orow[t] = d0 * rs * g[t] + bb[t];
  orow[t + 256] = d1 * rs * g[t + 256] + bb[t + 256];
}

// ---------------- bqq = bq @ Wqa + bqa ----------------
__global__ __launch_bounds__(512) void bqq_kernel(const float* __restrict__ bq,
    const float* __restrict__ Wqa, const float* __restrict__ bqa, float* __restrict__ bqq)
{
  __shared__ float s[EE];
  int t = threadIdx.x;
  s[t] = bq[t]; __syncthreads();
  float a0 = 0, a1 = 0, a2 = 0, a3 = 0;
  #pragma unroll 8
  for (int k = 0; k < EE; k += 4){
    a0 += s[k]     * Wqa[(size_t)(k)     * EE + t];
    a1 += s[k + 1] * Wqa[(size_t)(k + 1) * EE + t];
    a2 += s[k + 2] * Wqa[(size_t)(k + 2) * EE + t];
    a3 += s[k + 3] * Wqa[(size_t)(k + 3) * EE + t];
  }
  bqq[t] = bqa[t] + ((a0 + a1) + (a2 + a3));
}

// ---------------- decay -> rate ----------------
__global__ __launch_bounds__(512) void prep_decay(const float* __restrict__ dcA,
    const float* __restrict__ dcO, float* __restrict__ rA, float* __restrict__ rO)
{
  int t = threadIdx.x;
  rA[t] = expf(-fminf(fmaxf(dcA[t], 0.f), 15.f));
  rO[t] = expf(-fminf(fmaxf(dcO[t], 0.f), 15.f));
}

// ---------------- Wsyn pair-interleave: W2[k][2c+h] = Wsyn[k][c + 2048h] ----------------
__global__ __launch_bounds__(256) void permute_wsyn(const float* __restrict__ Wsyn,
    float* __restrict__ W2)
{
  int k = blockIdx.x;
  const float* src = Wsyn + (size_t)k * NSYN;
  float* dst = W2 + (size_t)k * NSYN;
  for (int c = threadIdx.x; c < 2048; c += 256){
    float2 v; v.x = src[c]; v.y = src[2048 + c];
    *reinterpret_cast<float2*>(&dst[2 * c]) = v;
  }
}

// ---------------- init state (+psum parity buffers) ----------------
__global__ __launch_bounds__(256) void init_kernel(const float* __restrict__ sa,
    const float* __restrict__ strace,
    const int* __restrict__ ol, const int* __restrict__ orr,
    float* __restrict__ act, float* __restrict__ tr,
    float* __restrict__ aA, float* __restrict__ bA,
    float* __restrict__ aO, float* __restrict__ bO,
    float* __restrict__ psum, float* __restrict__ psq)
{
  int tid = blockIdx.x * 256 + threadIdx.x;
  if (tid < 128){ psum[tid] = 0.f; psq[tid] = 0.f; }
  int b = tid >> 11, d = tid & 2047;
  act[(size_t)d * 64 + b] = sa[d];
  for (int m = 0; m < MM; m++)
    tr[((size_t)m * DD + d) * 64 + b] = strace[d * MM + m];
  if (tid < BB * NSS){
    int n = tid & (NSS - 1);
    int b2 = tid >> 9;
    aO[(size_t)b2 * NSS + n] = sa[ol[n]] * sa[orr[n]];
    bO[(size_t)b2 * NSS + n] = 1.f;
    aA[(size_t)b2 * NSS + n] = 0.f;
    bA[(size_t)b2 * NSS + n] = 0.f;
  }
}

// ---------------- K1: front (64 blocks = batch b) ----------------
__global__ __launch_bounds__(512) void k_front(
    const float* __restrict__ khT, const float* __restrict__ vh,
    const float* __restrict__ Wqq, const float* __restrict__ bqq,
    const float* __restrict__ Wo, const float* __restrict__ bo,
    const float* __restrict__ rA, const float* __restrict__ rO,
    const int* __restrict__ ial, const int* __restrict__ iar,
    const int* __restrict__ iol, const int* __restrict__ ior,
    float* __restrict__ aA, float* __restrict__ bA,
    float* __restrict__ aO, float* __restrict__ bO,
    const float* __restrict__ act, float* __restrict__ A,
    float* __restrict__ so_g, float* __restrict__ dout, int t)
{
  __shared__ float sm[4096];
  const int tid = threadIdx.x, b = blockIdx.x;
  const int lane = tid & 63, wv = tid >> 6;
  {
    int n = tid;
    if (t < TT){
      float pa = act[(size_t)ial[n] * 64 + b] * act[(size_t)iar[n] * 64 + b];
      float r = rA[n];
      float na = r * aA[(size_t)b * NSS + n] + pa;
      float nb = r * bA[(size_t)b * NSS + n] + 1.f;
      aA[(size_t)b * NSS + n] = na; bA[(size_t)b * NSS + n] = nb;
      sm[n] = na / sqrtf(nb);
    }
    if (t > 0){
      float po = act[(size_t)iol[n] * 64 + b] * act[(size_t)ior[n] * 64 + b];
      float r2 = rO[n];
      float na2 = r2 * aO[(size_t)b * NSS + n] + po;
      float nb2 = r2 * bO[(size_t)b * NSS + n] + 1.f;
      aO[(size_t)b * NSS + n] = na2; bO[(size_t)b * NSS + n] = nb2;
      float sv = na2 / sqrtf(nb2);
      so_g[(size_t)b * NSS + n] = sv;
      if (t == TT) dout[SYNC_OFF + (size_t)b * NSS + n] = sv;
    }
  }
  if (t >= TT) return;
  __syncthreads();
  // q2 = sA @ Wqq + bqq
  {
    int e = tid;
    float a0 = 0, a1 = 0, a2 = 0, a3 = 0;
    #pragma unroll 8
    for (int k = 0; k < EE; k += 4){
      a0 += sm[k]     * Wqq[(size_t)(k)     * EE + e];
      a1 += sm[k + 1] * Wqq[(size_t)(k + 1) * EE + e];
      a2 += sm[k + 2] * Wqq[(size_t)(k + 2) * EE + e];
      a3 += sm[k + 3] * Wqq[(size_t)(k + 3) * EE + e];
    }
    sm[1024 + e] = bqq[e] + ((a0 + a1) + (a2 + a3));
  }
  __syncthreads();
  // attention (wave = head)
  {
    int h = wv;
    int u = b * NHH + h;
    const float* K = khT + (size_t)u * HDD * SS;
    const float* V = vh + (size_t)u * SS * HDD;
    float c0 = 0, c1 = 0, c2 = 0, c3 = 0;
    for (int d2 = 0; d2 < HDD; d2++){
      float qd = sm[1024 + h * 64 + d2];
      const float* Kr = K + (size_t)d2 * SS;
      c0 += qd * Kr[lane];
      c1 += qd * Kr[64 + lane];
      c2 += qd * Kr[128 + lane];
      c3 += qd * Kr[192 + lane];
    }
    float s0 = c0 * 0.125f, s1 = c1 * 0.125f, s2 = c2 * 0.125f;
    float s3 = (lane < 4) ? c3 * 0.125f : -1e30f;
    float mx = fmaxf(fmaxf(s0, s1), fmaxf(s2, s3));
    #pragma unroll
    for (int off = 32; off > 0; off >>= 1)
      mx = fmaxf(mx, __shfl_xor(mx, off, 64));
    float e0 = expf(s0 - mx), e1 = expf(s1 - mx), e2 = expf(s2 - mx);
    float e3 = (lane < 4) ? expf(s3 - mx) : 0.f;
    float dn = e0 + e1 + e2 + e3;
    #pragma unroll
    for (int off = 32; off > 0; off >>= 1)
      dn += __shfl_xor(dn, off, 64);
    float* ps = sm + 1536 + h * 224;
    ps[lane] = e0; ps[64 + lane] = e1; ps[128 + lane] = e2;
    if (lane < 4) ps[192 + lane] = e3;
    float inv = 1.f / dn;
    float p0 = 0, p1 = 0, p2 = 0, p3 = 0;
    for (int s = 0; s < SS; s += 4){
      p0 += ps[s]     * V[(size_t)(s)     * 64 + lane];
      p1 += ps[s + 1] * V[(size_t)(s + 1) * 64 + lane];
      p2 += ps[s + 2] * V[(size_t)(s + 2) * 64 + lane];
      p3 += ps[s + 3] * V[(size_t)(s + 3) * 64 + lane];
    }
    sm[3328 + h * 64 + lane] = ((p0 + p1) + (p2 + p3)) * inv;
  }
  __syncthreads();
  // attnproj = ao @ Wo + bo -> A rows 0..511
  {
    int e = tid;
    float a0 = 0, a1 = 0, a2 = 0, a3 = 0;
    #pragma unroll 8
    for (int k = 0; k < EE; k += 4){
      a0 += sm[3328 + k]     * Wo[(size_t)(k)     * EE + e];
      a1 += sm[3328 + k + 1] * Wo[(size_t)(k + 1) * EE + e];
      a2 += sm[3328 + k + 2] * Wo[(size_t)(k + 2) * EE + e];
      a3 += sm[3328 + k + 3] * Wo[(size_t)(k + 3) * EE + e];
    }
    A[(size_t)e * 64 + b] = bo[e] + ((a0 + a1) + (a2 + a3));
  }
}

// ---------------- K2: interleaved-W2 GEMM (0..255, deep ILP) + out-GEMV (256..319) ----------------
__global__ __launch_bounds__(512) void k_syn2(
    const float* __restrict__ A, const float* __restrict__ W2,
    const float* __restrict__ bsyn, const float* __restrict__ Wout,
    const float* __restrict__ bout, const float* __restrict__ so_g,
    float* __restrict__ glupre, float* __restrict__ psum, float* __restrict__ psq,
    float* __restrict__ dout, int t)
{
  __shared__ float sm[8704];
  const int tid = threadIdx.x, blk = blockIdx.x;
  const int lane = tid & 63, wv = tid >> 6;
  const int par = t & 1;
  if (blk < 256){
    if (t >= TT) return;
    int c0 = blk * 8;
    int cc = 2 * c0;
    float acc[16];
    #pragma unroll
    for (int i = 0; i < 16; i++) acc[i] = 0.f;
    int kb = rfl(wv * 320);
    const float* Wp = W2 + (size_t)kb * NSYN + cc;
    const float* Ap = A + (size_t)kb * 64 + lane;
    for (int kt = 0; kt < 320; kt += 4){
      float a4[4];
      float4 w4[4][4];
      #pragma unroll
      for (int i = 0; i < 4; i++){
        a4[i] = Ap[(size_t)(kt + i) * 64];
        const float4* w = reinterpret_cast<const float4*>(Wp + (size_t)(kt + i) * NSYN);
        w4[i][0] = w[0]; w4[i][1] = w[1]; w4[i][2] = w[2]; w4[i][3] = w[3];
      }
      #pragma unroll
      for (int i = 0; i < 4; i++){
        float a = a4[i];
        acc[0]  += a * w4[i][0].x; acc[8]  += a * w4[i][0].y;
        acc[1]  += a * w4[i][0].z; acc[9]  += a * w4[i][0].w;
        acc[2]  += a * w4[i][1].x; acc[10] += a * w4[i][1].y;
        acc[3]  += a * w4[i][1].z; acc[11] += a * w4[i][1].w;
        acc[4]  += a * w4[i][2].x; acc[12] += a * w4[i][2].y;
        acc[5]  += a * w4[i][2].z; acc[13] += a * w4[i][2].w;
        acc[6]  += a * w4[i][3].x; acc[14] += a * w4[i][3].y;
        acc[7]  += a * w4[i][3].z; acc[15] += a * w4[i][3].w;
      }
    }
    #pragma unroll
    for (int i = 0; i < 16; i++) sm[wv * 1024 + i * 64 + lane] = acc[i];
    __syncthreads();
    {
      int ci = tid >> 6;
      int b = lane;
      float x0 = 0.f, x1 = 0.f;
      #pragma unroll
      for (int w = 0; w < 8; w++){
        x0 += sm[w * 1024 + ci * 64 + b];
        x1 += sm[w * 1024 + (8 + ci) * 64 + b];
      }
      x0 += bsyn[c0 + ci]; x1 += bsyn[2048 + c0 + ci];
      float u = x0 * sigm(x1);
      glupre[(size_t)(c0 + ci) * 64 + b] = u;
      sm[8192 + ci * 64 + b] = u;
    }
    __syncthreads();
    if (tid < 64){
      float s = 0.f, q = 0.f;
      #pragma unroll
      for (int c = 0; c < 8; c++){
        float uu = sm[8192 + c * 64 + tid];
        s += uu; q += uu * uu;
      }
      atomicAdd(&psum[par * 64 + tid], s);
      atomicAdd(&psq[par * 64 + tid], q);
    }
  } else {
    if (t == 0) return;
    int b = blk - 256;
    for (int k = tid; k < NSS; k += 512) sm[k] = so_g[(size_t)b * NSS + k];
    __syncthreads();
    #pragma unroll
    for (int half = 0; half < 2; half++){
      int n = tid + half * 512;
      if (n < OUTN){
        float a0 = 0, a1 = 0, a2 = 0, a3 = 0;
        #pragma unroll 8
        for (int k = 0; k < NSS; k += 4){
          a0 += sm[k]     * Wout[(size_t)(k)     * OUTN + n];
          a1 += sm[k + 1] * Wout[(size_t)(k + 1) * OUTN + n];
          a2 += sm[k + 2] * Wout[(size_t)(k + 2) * OUTN + n];
          a3 += sm[k + 3] * Wout[(size_t)(k + 3) * OUTN + n];
        }
        dout[((size_t)b * OUTN + n) * TT + (t - 1)] = bout[n] + ((a0 + a1) + (a2 + a3));
      }
    }
  }
}

// ---------------- K3: LN finalize + per-neuron MLP (256 blocks = 8 d's each) ----------------
__global__ __launch_bounds__(512) void k_nlm(
    const float* __restrict__ glupre, float* __restrict__ psum, float* __restrict__ psq,
    const float* __restrict__ gsyn, const float* __restrict__ bsn,
    const float* __restrict__ w1, const float* __restrict__ b1,
    const float* __restrict__ w2, const float* __restrict__ b2,
    float* __restrict__ tr, float* __restrict__ act, int t)
{
  __shared__ float sm[12800];
  const int tid = threadIdx.x, blk = blockIdx.x;
  const int lane = tid & 63, wv = tid >> 6;
  const int par = t & 1;
  if (blk == 0 && tid < 64){
    psum[(par ^ 1) * 64 + tid] = 0.f;
    psq[(par ^ 1) * 64 + tid] = 0.f;
  }
  int d0 = blk * 8;
  for (int idx = tid; idx < 1600; idx += 512){
    float4 va = *reinterpret_cast<const float4*>(w1 + (size_t)idx * DD + d0);
    float4 vb = *reinterpret_cast<const float4*>(w1 + (size_t)idx * DD + d0 + 4);
    sm[0 * 1600 + idx] = va.x; sm[1 * 1600 + idx] = va.y;
    sm[2 * 1600 + idx] = va.z; sm[3 * 1600 + idx] = va.w;
    sm[4 * 1600 + idx] = vb.x; sm[5 * 1600 + idx] = vb.y;
    sm[6 * 1600 + idx] = vb.z; sm[7 * 1600 + idx] = vb.w;
  }
  float ts = psum[par * 64 + lane];
  float tq = psq[par * 64 + lane];
  float mean = ts * (1.f / DD);
  float var = tq * (1.f / DD) - mean * mean;
  float rsv = 1.f / sqrtf(var + 1e-5f);
  __syncthreads();
  int dd = rfl(wv);
  int d = d0 + dd;
  float u = glupre[(size_t)d * 64 + lane];
  float snew = (u - mean) * rsv * gsyn[d] + bsn[d];
  int slot = t % MM;
  tr[((size_t)slot * DD + d) * 64 + lane] = snew;
  float hp[64];
  #pragma unroll
  for (int h = 0; h < 64; h++) hp[h] = b1[(size_t)d * 64 + h];
  for (int j = 0; j < MM - 1; j++){
    int js = (t + 1 + j) % MM;
    float tv = tr[((size_t)js * DD + d) * 64 + lane];
    const float* wr = &sm[dd * 1600 + j * 64];
    #pragma unroll
    for (int h4 = 0; h4 < 16; h4++){
      float4 w = *reinterpret_cast<const float4*>(&wr[h4 * 4]);
      hp[h4 * 4 + 0] += tv * w.x;
      hp[h4 * 4 + 1] += tv * w.y;
      hp[h4 * 4 + 2] += tv * w.z;
      hp[h4 * 4 + 3] += tv * w.w;
    }
  }
  {
    const float* wr = &sm[dd * 1600 + 24 * 64];
    #pragma unroll
    for (int h4 = 0; h4 < 16; h4++){
      float4 w = *reinterpret_cast<const float4*>(&wr[h4 * 4]);
      hp[h4 * 4 + 0] += snew * w.x;
      hp[h4 * 4 + 1] += snew * w.y;
      hp[h4 * 4 + 2] += snew * w.z;
      hp[h4 * 4 + 3] += snew * w.w;
    }
  }
  float o0 = b2[(size_t)d * 2], o1 = b2[(size_t)d * 2 + 1];
  #pragma unroll
  for (int h2 = 0; h2 < HNN; h2++){
    float hh = hp[h2] * sigm(hp[h2 + HNN]);
    o0 += hh * w2[((size_t)(h2 * 2)) * DD + d];
    o1 += hh * w2[((size_t)(h2 * 2 + 1)) * DD + d];
  }
  act[(size_t)d * 64 + lane] = o0 * sigm(o1);
}

// ---------------- certainty from stored predictions ----------------
__global__ __launch_bounds__(256) void cert_kernel(float* __restrict__ dout)
{
  int blk = blockIdx.x;
  int b = blk / TT, t = blk % TT;
  int tid = threadIdx.x;
  __shared__ float red[256];
  float vals[4];
  float mx = -1e30f;
  #pragma unroll
  for (int i = 0; i < 4; i++){
    int n = tid + i * 256;
    float v = (n < OUTN) ? dout[((size_t)b * OUTN + n) * TT + t] : -1e30f;
    vals[i] = v; mx = fmaxf(mx, v);
  }
  red[tid] = mx; __syncthreads();
  for (int st = 128; st > 0; st >>= 1){ if (tid < st) red[tid] = fmaxf(red[tid], red[tid + st]); __syncthreads(); }
  mx = red[0]; __syncthreads();
  float z = 0.f, s1 = 0.f;
  #pragma unroll
  for (int i = 0; i < 4; i++){
    int n = tid + i * 256;
    if (n < OUTN){
      float e = expf(vals[i] - mx);
      z += e; s1 += e * (vals[i] - mx);
    }
  }
  red[tid] = z; __syncthreads();
  for (int st = 128; st > 0; st >>= 1){ if (tid < st) red[tid] += red[tid + st]; __syncthreads(); }
  z = red[0]; __syncthreads();
  red[tid] = s1; __syncthreads();
  for (int st = 128; st > 0; st >>= 1){ if (tid < st) red[tid] += red[tid + st]; __syncthreads(); }
  s1 = red[0];
  if (tid == 0){
    float ne = (logf(z) - s1 / z) * (1.f / logf(1000.f));
    dout[CERT_OFF + ((size_t)b * 2 + 0) * TT + t] = ne;
    dout[CERT_OFF + ((size_t)b * 2 + 1) * TT + t] = 1.f - ne;
  }
}

extern "C" void kernel_launch(void* const* d_in, const int* in_sizes, int n_in,
                              void* d_out, int out_size, void* d_ws, size_t ws_size,
                              hipStream_t stream)
{
  const float* x    = (const float*)d_in[0];
  const float* Wkv  = (const float*)d_in[1];
  const float* bkv  = (const float*)d_in[2];
  const float* gkv  = (const float*)d_in[3];
  const float* bkv2 = (const float*)d_in[4];
  const float* Wq   = (const float*)d_in[5];
  const float* bq   = (const float*)d_in[6];
  const float* Wqa  = (const float*)d_in[7];
  const float* bqa  = (const float*)d_in[8];
  const float* Wka  = (const float*)d_in[9];
  const float* bka  = (const float*)d_in[10];
  const float* Wva  = (const float*)d_in[11];
  const float* bva  = (const float*)d_in[12];
  const float* Wo   = (const float*)d_in[13];
  const float* bo   = (const float*)d_in[14];
  const float* Wsyn = (const float*)d_in[15];
  const float* bsyn = (const float*)d_in[16];
  const float* gsyn = (const float*)d_in[17];
  const float* bsn  = (const float*)d_in[18];
  const float* w1   = (const float*)d_in[19];
  const float* b1   = (const float*)d_in[20];
  const float* w2   = (const float*)d_in[21];
  const float* b2   = (const float*)d_in[22];
  const float* sact = (const float*)d_in[23];
  const float* strc = (const float*)d_in[24];
  const float* dcA  = (const float*)d_in[25];
  const float* dcO  = (const float*)d_in[26];
  const float* Wout = (const float*)d_in[27];
  const float* bout = (const float*)d_in[28];
  const int* ial = (const int*)d_in[29];
  const int* iar = (const int*)d_in[30];
  const int* iol = (const int*)d_in[31];
  const int* ior = (const int*)d_in[32];

  char* ws = (char*)d_ws;
  float* khT  = (float*)(ws + 0);          // 25,690,112
  float* vh   = (float*)(ws + 25690112);   // -> 51,380,224
  float* B0   = (float*)(ws + 51380224);   // precompute scratch
  float* B1   = (float*)(ws + 64225280);   // -> 77,070,336
  // step-time region (overlays B0/B1):
  float* tr    = (float*)(ws + 51380224);  // 13,107,200 -> 64,487,424
  float* A     = (float*)(ws + 64487424);  // 655,360 (attnproj 512 rows | act 2048 rows)
  float* act   = A + 512 * 64;             // -> 65,142,784
  float* glupre= (float*)(ws + 65142784);  // 524,288 -> 65,667,072
  float* aA    = (float*)(ws + 65667072);  // 131,072
  float* bA    = (float*)(ws + 65798144);  // 131,072
  float* aO    = (float*)(ws + 65929216);  // 131,072
  float* bO    = (float*)(ws + 66060288);  // 131,072 -> 66,191,360
  float* so_g  = (float*)(ws + 66191360);  // 131,072 -> 66,322,432
  float* Wqq   = (float*)(ws + 66322432);  // 1,048,576 -> 67,371,008
  float* bqqb  = (float*)(ws + 67371008);  // 2,048
  float* rA    = (float*)(ws + 67373056);  // 2,048
  float* rO    = (float*)(ws + 67375104);  // 2,048
  float* psum  = (float*)(ws + 67377152);  // 512 (2 parities x 64)
  float* psq   = (float*)(ws + 67377664);  // 512
  float* W2    = (float*)(ws + 77070336);  // 41,943,040 -> 119,013,376 (r13-proven fit)
  float* dout = (float*)d_out;

  for (int c = 0; c < 2; c++){
    const float* xc = x + (size_t)c * 6272 * EE;
    sgemm<0><<<dim3(98, 8), 256, 0, stream>>>(xc, Wkv, bkv, B0, 6272, EE, EE, 0);
    ln_rows_kernel<<<6272, 256, 0, stream>>>(B0, gkv, bkv2, B1);
    sgemm<3><<<dim3(98, 8), 256, 0, stream>>>(B1, Wka, bka, khT, 6272, EE, EE, c * 6272);
    sgemm<1><<<dim3(98, 8), 256, 0, stream>>>(B1, Wva, bva, vh, 6272, EE, EE, c * 6272);
  }
  sgemm<0><<<dim3(8, 8), 256, 0, stream>>>(Wq, Wqa, nullptr, Wqq, EE, EE, EE, 0);
  bqq_kernel<<<1, 512, 0, stream>>>(bq, Wqa, bqa, bqqb);
  permute_wsyn<<<KSYN, 256, 0, stream>>>(Wsyn, W2);
  prep_decay<<<1, 512, 0, stream>>>(dcA, dcO, rA, rO);
  init_kernel<<<512, 256, 0, stream>>>(sact, strc, iol, ior, act, tr, aA, bA, aO, bO,
                                       psum, psq);

  for (int t = 0; t < TT; t++){
    k_front<<<64, 512, 0, stream>>>(khT, vh, Wqq, bqqb, Wo, bo, rA, rO,
                                    ial, iar, iol, ior, aA, bA, aO, bO,
                                    act, A, so_g, dout, t);
    k_syn2<<<320, 512, 0, stream>>>(A, W2, bsyn, Wout, bout, so_g,
                                    glupre, psum, psq, dout, t);
    k_nlm<<<256, 512, 0, stream>>>(glupre, psum, psq, gsyn, bsn,
                                   w1, b1, w2, b2, tr, act, t);
  }
  // tail: sO(49) + SYNC write, then out-GEMV(49)
  k_front<<<64, 512, 0, stream>>>(khT, vh, Wqq, bqqb, Wo, bo, rA, rO,
                                  ial, iar, iol, ior, aA, bA, aO, bO,
                                  act, A, so_g, dout, TT);
  k_syn2<<<320, 512, 0, stream>>>(A, W2, bsyn, Wout, bout, so_g,
                                  glupre, psum, psq, dout, TT);
  cert_kernel<<<BB * TT, 256, 0, stream>>>(dout);
}